// Round 3
// baseline (560.133 us; speedup 1.0000x reference)
//
#include <hip/hip_runtime.h>
#include <math.h>

typedef __bf16 bf16x8 __attribute__((ext_vector_type(8)));
typedef float  f32x4  __attribute__((ext_vector_type(4)));

#define DEV __device__ __forceinline__

DEV void gload16(const void* g, void* l) {
  __builtin_amdgcn_global_load_lds(
      (const __attribute__((address_space(1))) void*)g,
      (__attribute__((address_space(3))) void*)l, 16, 0, 0);
}

// ---------------------------------------------------------------------------
// Weight f32 [R][C] -> bf16 [C][R] (transposed) so GEMMs take B^T row-major.
// ---------------------------------------------------------------------------
__global__ __launch_bounds__(256) void transpose_cvt(
    const float* __restrict__ in, __bf16* __restrict__ outT, int R, int C) {
  __shared__ float t[32][33];
  const int c0 = blockIdx.x * 32, r0 = blockIdx.y * 32;
  const int tx = threadIdx.x, ty = threadIdx.y;  // (32,8)
#pragma unroll
  for (int i = 0; i < 4; i++)
    t[ty + 8 * i][tx] = in[(size_t)(r0 + ty + 8 * i) * C + c0 + tx];
  __syncthreads();
#pragma unroll
  for (int i = 0; i < 4; i++)
    outT[(size_t)(c0 + ty + 8 * i) * R + r0 + tx] = (__bf16)t[tx][ty + 8 * i];
}

// ---------------------------------------------------------------------------
// RMSNorm row kernel: f32 [rows][2048] -> bf16, 1 block/row, 8 elems/thread.
// ---------------------------------------------------------------------------
__global__ __launch_bounds__(256) void rmsnorm_kernel(
    const float* __restrict__ x, const float* __restrict__ g, __bf16* __restrict__ out) {
  const int r = blockIdx.x, t = threadIdx.x;
  const float4* xr = (const float4*)(x + (size_t)r * 2048);
  float4 a = xr[2 * t], b = xr[2 * t + 1];
  float ss = a.x * a.x + a.y * a.y + a.z * a.z + a.w * a.w +
             b.x * b.x + b.y * b.y + b.z * b.z + b.w * b.w;
#pragma unroll
  for (int mk = 1; mk < 64; mk <<= 1) ss += __shfl_xor(ss, mk);
  __shared__ float red[4];
  if ((t & 63) == 0) red[t >> 6] = ss;
  __syncthreads();
  const float sc = rsqrtf((red[0] + red[1] + red[2] + red[3]) * (1.0f / 2048.0f) + 1e-6f);
  const float4* gr = (const float4*)g;
  float4 ga = gr[2 * t], gb = gr[2 * t + 1];
  bf16x8 ov;
  ov[0] = (__bf16)(a.x * sc * ga.x); ov[1] = (__bf16)(a.y * sc * ga.y);
  ov[2] = (__bf16)(a.z * sc * ga.z); ov[3] = (__bf16)(a.w * sc * ga.w);
  ov[4] = (__bf16)(b.x * sc * gb.x); ov[5] = (__bf16)(b.y * sc * gb.y);
  ov[6] = (__bf16)(b.z * sc * gb.z); ov[7] = (__bf16)(b.w * sc * gb.w);
  *(bf16x8*)(out + (size_t)r * 2048 + t * 8) = ov;
}

// ---------------------------------------------------------------------------
// GEMM 128x128 (m97 structure) — kept for N=2048 outputs (out/proj).
// ---------------------------------------------------------------------------
template <int EPI>
__global__ __launch_bounds__(256) void gemm_bt(
    const __bf16* __restrict__ A, const __bf16* __restrict__ BT,
    void* __restrict__ Cout, const float* __restrict__ res, int M, int N, int K) {
  __shared__ char lds[32768];
  char* As = lds;
  char* Bs = lds + 16384;
  const int tid = threadIdx.x;
  const int lane = tid & 63;
  const int bn = blockIdx.x, bm = blockIdx.y;
  const int wm = tid >> 7, wn = (tid >> 6) & 1;

  f32x4 acc[4][4];
#pragma unroll
  for (int i = 0; i < 4; i++)
#pragma unroll
    for (int j = 0; j < 4; j++) acc[i][j] = (f32x4){0.f, 0.f, 0.f, 0.f};

  const size_t strideA = (size_t)K * 2;
  const char* ga[4];
  const char* gb[4];
#pragma unroll
  for (int t = 0; t < 4; t++) {
    int gg = t * 256 + tid;
    int row = gg >> 3, slot = gg & 7;
    ga[t] = (const char*)A + (size_t)(bm * 128 + row) * strideA + ((slot ^ (row & 7)) << 4);
    gb[t] = (const char*)BT + (size_t)(bn * 128 + row) * strideA + ((slot ^ (row & 7)) << 4);
  }

  for (int k0 = 0; k0 < K; k0 += 64) {
    __syncthreads();
#pragma unroll
    for (int t = 0; t < 4; t++) {
      int gg = t * 256 + tid;
      gload16(ga[t], As + gg * 16);
      gload16(gb[t], Bs + gg * 16);
      ga[t] += 128;
      gb[t] += 128;
    }
    __syncthreads();
#pragma unroll
    for (int kk = 0; kk < 2; kk++) {
      bf16x8 a[4], b[4];
      const int c16 = kk * 4 + (lane >> 4);
#pragma unroll
      for (int i = 0; i < 4; i++) {
        int ra = wm * 64 + i * 16 + (lane & 15);
        a[i] = *(const bf16x8*)(As + ra * 128 + ((c16 ^ (ra & 7)) << 4));
        int rb = wn * 64 + i * 16 + (lane & 15);
        b[i] = *(const bf16x8*)(Bs + rb * 128 + ((c16 ^ (rb & 7)) << 4));
      }
#pragma unroll
      for (int i = 0; i < 4; i++)
#pragma unroll
        for (int j = 0; j < 4; j++)
          acc[i][j] = __builtin_amdgcn_mfma_f32_16x16x32_bf16(a[i], b[j], acc[i][j], 0, 0, 0);
    }
  }

#pragma unroll
  for (int i = 0; i < 4; i++)
#pragma unroll
    for (int j = 0; j < 4; j++)
#pragma unroll
      for (int r = 0; r < 4; r++) {
        int row = bm * 128 + wm * 64 + i * 16 + ((lane >> 4) << 2) + r;
        int col = bn * 128 + wn * 64 + j * 16 + (lane & 15);
        size_t idx = (size_t)row * N + col;
        float v = acc[i][j][r];
        if (EPI == 0) {
          ((__bf16*)Cout)[idx] = (__bf16)v;
        } else if (EPI == 1) {
          ((float*)Cout)[idx] = v + res[idx];
        } else {
          float u = 0.7978845608028654f * (v + 0.044715f * v * v * v);
          ((__bf16*)Cout)[idx] = (__bf16)(0.5f * v * (1.0f + tanhf(u)));
        }
      }
}

// ---------------------------------------------------------------------------
// GEMM 256x256, BK=64, 8 waves (2M x 4N, each 128x64), 4-phase K-loop with
// counted vmcnt(8) (T3+T4), raw barriers, setprio around MFMA (T5), XOR-
// swizzled double-buffered LDS (T2). LDS = 2*(32K A + 32K B) = 128 KiB.
// Phase p reads: p0: A-half0(8)+B-q0(4); p1: B-q1(4); p2: A-half1(8); p3: -.
// Tile kt+1's 8 global_load_lds are issued at the top of kt -> one full
// K-tile of latency slack; wait is vmcnt(8), never 0.
// ---------------------------------------------------------------------------
template <int EPI>
__global__ __launch_bounds__(512, 2) void gemm256(
    const __bf16* __restrict__ A, const __bf16* __restrict__ BT,
    void* __restrict__ Cout, const float* __restrict__ res, int M, int N, int K) {
  __shared__ char lds[131072];
  const int tid = threadIdx.x;   // 0..511
  const int lane = tid & 63;
  const int w = tid >> 6;        // 0..7
  const int wm = w >> 2;         // 0..1  (M half: 128 rows)
  const int wn = w & 3;          // 0..3  (N quarter: 64 cols)
  const int bn = blockIdx.x, bm = blockIdx.y;

  f32x4 acc[8][4];
#pragma unroll
  for (int i = 0; i < 8; i++)
#pragma unroll
    for (int j = 0; j < 4; j++) acc[i][j] = (f32x4){0.f, 0.f, 0.f, 0.f};

  const size_t strideA = (size_t)K * 2;
  const char* gA[4];
  const char* gB[4];
#pragma unroll
  for (int t = 0; t < 4; t++) {
    int gg = t * 512 + tid;
    int row = gg >> 3, slot = gg & 7;
    gA[t] = (const char*)A + (size_t)(bm * 256 + row) * strideA + ((slot ^ (row & 7)) << 4);
    gB[t] = (const char*)BT + (size_t)(bn * 256 + row) * strideA + ((slot ^ (row & 7)) << 4);
  }

  auto stage8 = [&](int kt, int buf) {
    const size_t koff = (size_t)kt * 128;
    char* Ad = lds + buf * 32768;
    char* Bd = lds + 65536 + buf * 32768;
#pragma unroll
    for (int t = 0; t < 4; t++) {
      gload16(gA[t] + koff, Ad + (t * 512 + tid) * 16);
      gload16(gB[t] + koff, Bd + (t * 512 + tid) * 16);
    }
  };

  const int NT = K >> 6;
  stage8(0, 0);  // prologue

  for (int kt = 0; kt < NT; ++kt) {
    const int buf = kt & 1;
    const char* Ab = lds + buf * 32768;
    const char* Bb = lds + 65536 + buf * 32768;
    const int ktp = (kt + 1 < NT) ? kt + 1 : kt;  // clamp keeps vmcnt uniform
    stage8(ktp, buf ^ 1);
    asm volatile("s_waitcnt vmcnt(8)" ::: "memory");
    __builtin_amdgcn_s_barrier();

    bf16x8 a[4][2], b0[2][2], b1[2][2];
    // --- phase 0: A-half0 x B-quarter0 ---
#pragma unroll
    for (int i = 0; i < 4; i++)
#pragma unroll
      for (int kk = 0; kk < 2; kk++) {
        int ra = wm * 128 + i * 16 + (lane & 15);
        int c16 = kk * 4 + (lane >> 4);
        a[i][kk] = *(const bf16x8*)(Ab + ra * 128 + ((c16 ^ (ra & 7)) << 4));
      }
#pragma unroll
    for (int j = 0; j < 2; j++)
#pragma unroll
      for (int kk = 0; kk < 2; kk++) {
        int rb = wn * 64 + j * 16 + (lane & 15);
        int c16 = kk * 4 + (lane >> 4);
        b0[j][kk] = *(const bf16x8*)(Bb + rb * 128 + ((c16 ^ (rb & 7)) << 4));
      }
    __builtin_amdgcn_s_setprio(1);
#pragma unroll
    for (int i = 0; i < 4; i++)
#pragma unroll
      for (int j = 0; j < 2; j++)
#pragma unroll
        for (int kk = 0; kk < 2; kk++)
          acc[i][j] = __builtin_amdgcn_mfma_f32_16x16x32_bf16(a[i][kk], b0[j][kk], acc[i][j], 0, 0, 0);
    __builtin_amdgcn_s_setprio(0);
#pragma unroll
    for (int j = 0; j < 2; j++)
#pragma unroll
      for (int kk = 0; kk < 2; kk++) {
        int rb = wn * 64 + (2 + j) * 16 + (lane & 15);
        int c16 = kk * 4 + (lane >> 4);
        b1[j][kk] = *(const bf16x8*)(Bb + rb * 128 + ((c16 ^ (rb & 7)) << 4));
      }
    __builtin_amdgcn_s_barrier();
    // --- phase 1: A-half0 x B-quarter1 ---
    __builtin_amdgcn_s_setprio(1);
#pragma unroll
    for (int i = 0; i < 4; i++)
#pragma unroll
      for (int j = 0; j < 2; j++)
#pragma unroll
        for (int kk = 0; kk < 2; kk++)
          acc[i][2 + j] = __builtin_amdgcn_mfma_f32_16x16x32_bf16(a[i][kk], b1[j][kk], acc[i][2 + j], 0, 0, 0);
    __builtin_amdgcn_s_setprio(0);
#pragma unroll
    for (int i = 0; i < 4; i++)
#pragma unroll
      for (int kk = 0; kk < 2; kk++) {
        int ra = wm * 128 + 64 + i * 16 + (lane & 15);
        int c16 = kk * 4 + (lane >> 4);
        a[i][kk] = *(const bf16x8*)(Ab + ra * 128 + ((c16 ^ (ra & 7)) << 4));
      }
    __builtin_amdgcn_s_barrier();
    // --- phase 2: A-half1 x B-quarter1 ---
    __builtin_amdgcn_s_setprio(1);
#pragma unroll
    for (int i = 0; i < 4; i++)
#pragma unroll
      for (int j = 0; j < 2; j++)
#pragma unroll
        for (int kk = 0; kk < 2; kk++)
          acc[4 + i][2 + j] = __builtin_amdgcn_mfma_f32_16x16x32_bf16(a[i][kk], b1[j][kk], acc[4 + i][2 + j], 0, 0, 0);
    __builtin_amdgcn_s_setprio(0);
    __builtin_amdgcn_s_barrier();
    // --- phase 3: A-half1 x B-quarter0 ---
    __builtin_amdgcn_s_setprio(1);
#pragma unroll
    for (int i = 0; i < 4; i++)
#pragma unroll
      for (int j = 0; j < 2; j++)
#pragma unroll
        for (int kk = 0; kk < 2; kk++)
          acc[4 + i][j] = __builtin_amdgcn_mfma_f32_16x16x32_bf16(a[i][kk], b0[j][kk], acc[4 + i][j], 0, 0, 0);
    __builtin_amdgcn_s_setprio(0);
    __builtin_amdgcn_s_barrier();
  }

#pragma unroll
  for (int i = 0; i < 8; i++)
#pragma unroll
    for (int j = 0; j < 4; j++)
#pragma unroll
      for (int r = 0; r < 4; r++) {
        int row = bm * 256 + wm * 128 + i * 16 + ((lane >> 4) << 2) + r;
        int col = bn * 256 + wn * 64 + j * 16 + (lane & 15);
        size_t idx = (size_t)row * N + col;
        float v = acc[i][j][r];
        if (EPI == 0) {
          ((__bf16*)Cout)[idx] = (__bf16)v;
        } else if (EPI == 1) {
          ((float*)Cout)[idx] = v + res[idx];
        } else {
          float u = 0.7978845608028654f * (v + 0.044715f * v * v * v);
          ((__bf16*)Cout)[idx] = (__bf16)(0.5f * v * (1.0f + tanhf(u)));
        }
      }
}

// ---------------------------------------------------------------------------
// RoPE tables: cos/sin [2048][64] f32 (cos at [0], sin at +131072 elems).
// ---------------------------------------------------------------------------
__global__ __launch_bounds__(256) void rope_tables(float* __restrict__ tab) {
  const int idx = blockIdx.x * 256 + threadIdx.x;  // 131072
  const int s = idx >> 6, j = idx & 63;
  const float inv = powf(10000.0f, -(float)j / 64.0f);
  const float a = (float)s * inv;
  tab[idx] = cosf(a);
  tab[131072 + idx] = sinf(a);
}

// ---------------------------------------------------------------------------
// RoPE apply + head split: qkv bf16 [B*S][6144] -> q_r,k_r bf16 [B][H][S][128].
// ---------------------------------------------------------------------------
__global__ __launch_bounds__(256) void rope_apply(
    const __bf16* __restrict__ qkv, const float* __restrict__ tab,
    __bf16* __restrict__ qr, __bf16* __restrict__ kr) {
  const int idx = blockIdx.x * 256 + threadIdx.x;  // 4194304
  const int j = idx & 63;
  const int h = (idx >> 6) & 15;
  const int s = (idx >> 10) & 2047;
  const int b = idx >> 21;
  const float c = tab[(s << 6) + j], sn = tab[131072 + (s << 6) + j];
  const size_t qi = ((size_t)(b * 2048 + s)) * 6144 + h * 128 + 2 * j;
  const size_t qo = ((size_t)((b * 16 + h) * 2048 + s)) * 128 + 2 * j;
  {
    float e = (float)qkv[qi], o = (float)qkv[qi + 1];
    qr[qo] = (__bf16)(e * c - o * sn);
    qr[qo + 1] = (__bf16)(o * c + e * sn);
  }
  {
    float e = (float)qkv[qi + 2048], o = (float)qkv[qi + 2048 + 1];
    kr[qo] = (__bf16)(e * c - o * sn);
    kr[qo + 1] = (__bf16)(o * c + e * sn);
  }
}

// ---------------------------------------------------------------------------
// V transpose: qkv v-part [B*S][6144] -> vt bf16 [B][H][128][S].
// ---------------------------------------------------------------------------
__global__ __launch_bounds__(256) void v_transpose(
    const __bf16* __restrict__ qkv, __bf16* __restrict__ vt) {
  __shared__ __bf16 t[32][33];
  const int s0 = blockIdx.x * 32, d0 = blockIdx.y * 32, bh = blockIdx.z;
  const int b = bh >> 4, h = bh & 15;
  const int tx = threadIdx.x, ty = threadIdx.y;  // (32,8)
#pragma unroll
  for (int i = 0; i < 4; i++)
    t[ty + 8 * i][tx] =
        qkv[((size_t)(b * 2048 + s0 + ty + 8 * i)) * 6144 + 4096 + h * 128 + d0 + tx];
  __syncthreads();
#pragma unroll
  for (int i = 0; i < 4; i++)
    vt[((size_t)bh * 128 + d0 + ty + 8 * i) * 2048 + s0 + tx] = t[tx][ty + 8 * i];
}

// ---------------------------------------------------------------------------
// Flash attention (causal), load-balanced + pipelined (unchanged from R1).
// ---------------------------------------------------------------------------
__global__ __launch_bounds__(256) void flash_attn(
    const __bf16* __restrict__ qg, const __bf16* __restrict__ kg,
    const __bf16* __restrict__ vtg, __bf16* __restrict__ og) {
  __shared__ char lds[73728];
  const int tid = threadIdx.x, lane = tid & 63, w = tid >> 6;
  const int h = blockIdx.y, b = blockIdx.z;
  const int bh = b * 16 + h;
  const __bf16* qb = qg + (size_t)bh * 2048 * 128;
  const char* kbb = (const char*)(kg + (size_t)bh * 2048 * 128);
  const char* vbb = (const char*)(vtg + (size_t)bh * 128 * 2048);
  char* Pw = lds + 65536 + w * 2048;

  const char* gK[4];
  const char* gV[4];
#pragma unroll
  for (int t = 0; t < 4; t++) {
    int gg = t * 256 + tid;
    int rk = gg >> 4, sk = gg & 15;
    gK[t] = kbb + rk * 256 + ((sk ^ (rk & 15)) << 4);
    int rv = gg >> 3, sv = gg & 7;
    gV[t] = vbb + rv * 4096 + ((sv ^ (rv & 7)) << 4);
  }

  const float SL2E = 0.08838834764831845f * 1.4426950408889634f;  // scale*log2(e)

  auto run_qtile = [&](int qt) {
    const int qrow0 = qt * 64 + w * 16;
    bf16x8 qf[4];
#pragma unroll
    for (int c = 0; c < 4; c++) {
      bf16x8 raw = *(const bf16x8*)(qb + (size_t)(qrow0 + (lane & 15)) * 128 +
                                    c * 32 + ((lane >> 4) << 3));
#pragma unroll
      for (int e = 0; e < 8; e++) qf[c][e] = (__bf16)((float)raw[e] * SL2E);
    }
    float m[4], ls[4];
    f32x4 o[8];
#pragma unroll
    for (int r = 0; r < 4; r++) { m[r] = -__builtin_inff(); ls[r] = 0.f; }
#pragma unroll
    for (int n = 0; n < 8; n++) o[n] = (f32x4){0.f, 0.f, 0.f, 0.f};

#pragma unroll
    for (int t = 0; t < 4; t++) {
      int gg = t * 256 + tid;
      gload16(gK[t], lds + gg * 16);
      gload16(gV[t], lds + 32768 + gg * 16);
    }

    for (int kt = 0; kt <= qt; kt++) {
      const int cur = kt & 1;
      char* Ks = lds + cur * 16384;
      char* Vs = lds + 32768 + cur * 16384;
      if (kt < qt) {
        char* Kd = lds + (cur ^ 1) * 16384;
        char* Vd = lds + 32768 + (cur ^ 1) * 16384;
#pragma unroll
        for (int t = 0; t < 4; t++) {
          int gg = t * 256 + tid;
          gload16(gK[t] + (size_t)(kt + 1) * 16384, Kd + gg * 16);
          gload16(gV[t] + (size_t)(kt + 1) * 128, Vd + gg * 16);
        }
        asm volatile("s_waitcnt vmcnt(8)" ::: "memory");
      } else {
        asm volatile("s_waitcnt vmcnt(0)" ::: "memory");
      }
      __builtin_amdgcn_s_barrier();

      f32x4 s[4];
      __builtin_amdgcn_s_setprio(1);
#pragma unroll
      for (int n = 0; n < 4; n++) {
        s[n] = (f32x4){0.f, 0.f, 0.f, 0.f};
#pragma unroll
        for (int c = 0; c < 4; c++) {
          int krow = n * 16 + (lane & 15);
          int c16 = c * 4 + (lane >> 4);
          bf16x8 kf = *(const bf16x8*)(Ks + krow * 256 + ((c16 ^ (krow & 15)) << 4));
          s[n] = __builtin_amdgcn_mfma_f32_16x16x32_bf16(qf[c], kf, s[n], 0, 0, 0);
        }
      }
      __builtin_amdgcn_s_setprio(0);

      float p[4][4], fc[4];
      const bool diag = (kt == qt);
#pragma unroll
      for (int r = 0; r < 4; r++) {
        if (diag) {
          const int qrow = qrow0 + ((lane >> 4) << 2) + r;
#pragma unroll
          for (int n = 0; n < 4; n++) {
            int col = kt * 64 + n * 16 + (lane & 15);
            if (col > qrow) s[n][r] = -__builtin_inff();
          }
        }
        float tmx = fmaxf(fmaxf(s[0][r], s[1][r]), fmaxf(s[2][r], s[3][r]));
#pragma unroll
        for (int mk = 1; mk < 16; mk <<= 1) tmx = fmaxf(tmx, __shfl_xor(tmx, mk));
        float nm;
        if (tmx <= m[r] + 8.f) {
          nm = m[r];
          fc[r] = 1.f;
        } else {
          nm = tmx;
          fc[r] = exp2f(m[r] - nm);
          m[r] = nm;
        }
        float sum = 0.f;
#pragma unroll
        for (int n = 0; n < 4; n++) {
          float pv = exp2f(s[n][r] - nm);
          p[n][r] = pv;
          sum += pv;
        }
#pragma unroll
        for (int mk = 1; mk < 16; mk <<= 1) sum += __shfl_xor(sum, mk);
        ls[r] = ls[r] * fc[r] + sum;
      }
      if ((fc[0] < 1.f) | (fc[1] < 1.f) | (fc[2] < 1.f) | (fc[3] < 1.f)) {
#pragma unroll
        for (int n = 0; n < 8; n++) {
          o[n][0] *= fc[0]; o[n][1] *= fc[1]; o[n][2] *= fc[2]; o[n][3] *= fc[3];
        }
      }

#pragma unroll
      for (int n = 0; n < 4; n++)
#pragma unroll
        for (int r = 0; r < 4; r++) {
          int prow = ((lane >> 4) << 2) + r;
          int col = n * 16 + (lane & 15);
          int ch = col >> 3;
          *(__bf16*)(Pw + prow * 128 + ((ch ^ (prow & 7)) << 4) + ((col & 7) << 1)) =
              (__bf16)p[n][r];
        }

      __builtin_amdgcn_s_setprio(1);
#pragma unroll
      for (int kk = 0; kk < 2; kk++) {
        int prow = lane & 15;
        int pc = kk * 4 + (lane >> 4);
        bf16x8 pf = *(const bf16x8*)(Pw + prow * 128 + ((pc ^ (prow & 7)) << 4));
#pragma unroll
        for (int n = 0; n < 8; n++) {
          int vr = n * 16 + (lane & 15);
          bf16x8 vf = *(const bf16x8*)(Vs + vr * 128 + ((pc ^ (vr & 7)) << 4));
          o[n] = __builtin_amdgcn_mfma_f32_16x16x32_bf16(pf, vf, o[n], 0, 0, 0);
        }
      }
      __builtin_amdgcn_s_setprio(0);
      __builtin_amdgcn_s_barrier();
    }

    float inv[4];
#pragma unroll
    for (int r = 0; r < 4; r++) inv[r] = 1.0f / ls[r];
#pragma unroll
    for (int n = 0; n < 8; n++)
#pragma unroll
      for (int r = 0; r < 4; r++) {
        int qrow = qrow0 + ((lane >> 4) << 2) + r;
        og[(size_t)(b * 2048 + qrow) * 2048 + h * 128 + n * 16 + (lane & 15)] =
            (__bf16)(o[n][r] * inv[r]);
      }
  };

  run_qtile(31 - (int)blockIdx.x);
  run_qtile((int)blockIdx.x);
}

// ---------------------------------------------------------------------------
extern "C" void kernel_launch(void* const* d_in, const int* in_sizes, int n_in,
                              void* d_out, int out_size, void* d_ws, size_t ws_size,
                              hipStream_t stream) {
  const float* x = (const float*)d_in[0];
  const float* w_qkv = (const float*)d_in[1];
  const float* w_out = (const float*)d_in[2];
  const float* w_fc = (const float*)d_in[3];
  const float* w_proj = (const float*)d_in[4];
  const float* g_in = (const float*)d_in[5];
  const float* g_ff = (const float*)d_in[6];
  float* out = (float*)d_out;
  char* ws = (char*)d_ws;

  constexpr size_t O_WQKV = 0;           // bf16 [6144][2048]
  constexpr size_t O_WOUT = 25165824;    // bf16 [2048][2048]
  constexpr size_t O_WFC = 33554432;     // bf16 [4096][2048]
  constexpr size_t O_WPROJ = 50331648;   // bf16 [2048][4096]
  constexpr size_t O_H = 67108864;       // bf16 [4096][2048]
  constexpr size_t O_QKV = 83886080;     // bf16 [4096][6144] (later fcact [4096][4096])
  constexpr size_t O_Q = 134217728;      // bf16 [2][16][2048][128]
  constexpr size_t O_K = 150994944;
  constexpr size_t O_VT = 167772160;     // bf16 [2][16][128][2048]
  constexpr size_t O_TAB = 184549376;    // f32 cos/sin [2][2048][64]
  constexpr size_t O_ATTN = 185597952;   // bf16 [4096][2048]
  constexpr size_t O_X1 = 202375168;     // f32 [4096][2048]

  __bf16* wqkvT = (__bf16*)(ws + O_WQKV);
  __bf16* woutT = (__bf16*)(ws + O_WOUT);
  __bf16* wfcT = (__bf16*)(ws + O_WFC);
  __bf16* wprojT = (__bf16*)(ws + O_WPROJ);
  __bf16* h = (__bf16*)(ws + O_H);
  __bf16* qkv = (__bf16*)(ws + O_QKV);
  __bf16* fcact = (__bf16*)(ws + O_QKV);
  __bf16* qr = (__bf16*)(ws + O_Q);
  __bf16* kr = (__bf16*)(ws + O_K);
  __bf16* vt = (__bf16*)(ws + O_VT);
  float* tab = (float*)(ws + O_TAB);
  __bf16* attn = (__bf16*)(ws + O_ATTN);
  float* x1 = (float*)(ws + O_X1);

  const dim3 tb(32, 8);
  transpose_cvt<<<dim3(6144 / 32, 2048 / 32), tb, 0, stream>>>(w_qkv, wqkvT, 2048, 6144);
  transpose_cvt<<<dim3(2048 / 32, 2048 / 32), tb, 0, stream>>>(w_out, woutT, 2048, 2048);
  transpose_cvt<<<dim3(4096 / 32, 2048 / 32), tb, 0, stream>>>(w_fc, wfcT, 2048, 4096);
  transpose_cvt<<<dim3(2048 / 32, 4096 / 32), tb, 0, stream>>>(w_proj, wprojT, 4096, 2048);

  // h = rmsnorm(x, g_in)
  rmsnorm_kernel<<<4096, 256, 0, stream>>>(x, g_in, h);
  // qkv = h @ w_qkv  (256^2 8-phase)
  gemm256<0><<<dim3(24, 16), 512, 0, stream>>>(h, wqkvT, (void*)qkv, nullptr, 4096, 6144, 2048);
  // rope
  rope_tables<<<512, 256, 0, stream>>>(tab);
  rope_apply<<<16384, 256, 0, stream>>>(qkv, tab, qr, kr);
  v_transpose<<<dim3(64, 4, 32), tb, 0, stream>>>(qkv, vt);
  // attention
  flash_attn<<<dim3(16, 16, 2), 256, 0, stream>>>(qr, kr, vt, attn);
  // x1 = x + attn @ w_out
  gemm_bt<1><<<dim3(16, 32), 256, 0, stream>>>(attn, woutT, (void*)x1, x, 4096, 2048, 2048);
  // h2 = rmsnorm(x1, g_ff)
  rmsnorm_kernel<<<4096, 256, 0, stream>>>(x1, g_ff, h);
  // fcact = gelu(h2 @ w_fc)  (256^2 8-phase)
  gemm256<2><<<dim3(16, 16), 512, 0, stream>>>(h, wfcT, (void*)fcact, nullptr, 4096, 4096, 2048);
  // out = x1 + fcact @ w_proj
  gemm_bt<1><<<dim3(16, 32), 256, 0, stream>>>(fcact, wprojT, (void*)out, x1, 4096, 2048, 4096);
}

// Round 4
// 520.938 us; speedup vs baseline: 1.0752x; 1.0752x over previous
//
#include <hip/hip_runtime.h>
#include <math.h>

typedef __bf16 bf16x8 __attribute__((ext_vector_type(8)));
typedef float  f32x4  __attribute__((ext_vector_type(4)));

#define DEV __device__ __forceinline__

DEV void gload16(const void* g, void* l) {
  __builtin_amdgcn_global_load_lds(
      (const __attribute__((address_space(1))) void*)g,
      (__attribute__((address_space(3))) void*)l, 16, 0, 0);
}

// ---------------------------------------------------------------------------
// Weight f32 [R][C] -> bf16 [C][R] (transposed) so GEMMs take B^T row-major.
// ---------------------------------------------------------------------------
__global__ __launch_bounds__(256) void transpose_cvt(
    const float* __restrict__ in, __bf16* __restrict__ outT, int R, int C) {
  __shared__ float t[32][33];
  const int c0 = blockIdx.x * 32, r0 = blockIdx.y * 32;
  const int tx = threadIdx.x, ty = threadIdx.y;  // (32,8)
#pragma unroll
  for (int i = 0; i < 4; i++)
    t[ty + 8 * i][tx] = in[(size_t)(r0 + ty + 8 * i) * C + c0 + tx];
  __syncthreads();
#pragma unroll
  for (int i = 0; i < 4; i++)
    outT[(size_t)(c0 + ty + 8 * i) * R + r0 + tx] = (__bf16)t[tx][ty + 8 * i];
}

// ---------------------------------------------------------------------------
// RMSNorm row kernel: f32 [rows][2048] -> bf16, 1 block/row, 8 elems/thread.
// ---------------------------------------------------------------------------
__global__ __launch_bounds__(256) void rmsnorm_kernel(
    const float* __restrict__ x, const float* __restrict__ g, __bf16* __restrict__ out) {
  const int r = blockIdx.x, t = threadIdx.x;
  const float4* xr = (const float4*)(x + (size_t)r * 2048);
  float4 a = xr[2 * t], b = xr[2 * t + 1];
  float ss = a.x * a.x + a.y * a.y + a.z * a.z + a.w * a.w +
             b.x * b.x + b.y * b.y + b.z * b.z + b.w * b.w;
#pragma unroll
  for (int mk = 1; mk < 64; mk <<= 1) ss += __shfl_xor(ss, mk);
  __shared__ float red[4];
  if ((t & 63) == 0) red[t >> 6] = ss;
  __syncthreads();
  const float sc = rsqrtf((red[0] + red[1] + red[2] + red[3]) * (1.0f / 2048.0f) + 1e-6f);
  const float4* gr = (const float4*)g;
  float4 ga = gr[2 * t], gb = gr[2 * t + 1];
  bf16x8 ov;
  ov[0] = (__bf16)(a.x * sc * ga.x); ov[1] = (__bf16)(a.y * sc * ga.y);
  ov[2] = (__bf16)(a.z * sc * ga.z); ov[3] = (__bf16)(a.w * sc * ga.w);
  ov[4] = (__bf16)(b.x * sc * gb.x); ov[5] = (__bf16)(b.y * sc * gb.y);
  ov[6] = (__bf16)(b.z * sc * gb.z); ov[7] = (__bf16)(b.w * sc * gb.w);
  *(bf16x8*)(out + (size_t)r * 2048 + t * 8) = ov;
}

// ---------------------------------------------------------------------------
// GEMM 128x128 (m97 structure, measured 895 TF here) — all four GEMMs.
// EPI: 0 = bf16 store, 1 = f32 store + residual, 2 = gelu -> bf16.
// ---------------------------------------------------------------------------
template <int EPI>
__global__ __launch_bounds__(256) void gemm_bt(
    const __bf16* __restrict__ A, const __bf16* __restrict__ BT,
    void* __restrict__ Cout, const float* __restrict__ res, int M, int N, int K) {
  __shared__ char lds[32768];
  char* As = lds;
  char* Bs = lds + 16384;
  const int tid = threadIdx.x;
  const int lane = tid & 63;
  const int bn = blockIdx.x, bm = blockIdx.y;
  const int wm = tid >> 7, wn = (tid >> 6) & 1;

  f32x4 acc[4][4];
#pragma unroll
  for (int i = 0; i < 4; i++)
#pragma unroll
    for (int j = 0; j < 4; j++) acc[i][j] = (f32x4){0.f, 0.f, 0.f, 0.f};

  const size_t strideA = (size_t)K * 2;
  const char* ga[4];
  const char* gb[4];
#pragma unroll
  for (int t = 0; t < 4; t++) {
    int gg = t * 256 + tid;
    int row = gg >> 3, slot = gg & 7;
    ga[t] = (const char*)A + (size_t)(bm * 128 + row) * strideA + ((slot ^ (row & 7)) << 4);
    gb[t] = (const char*)BT + (size_t)(bn * 128 + row) * strideA + ((slot ^ (row & 7)) << 4);
  }

  for (int k0 = 0; k0 < K; k0 += 64) {
    __syncthreads();
#pragma unroll
    for (int t = 0; t < 4; t++) {
      int gg = t * 256 + tid;
      gload16(ga[t], As + gg * 16);
      gload16(gb[t], Bs + gg * 16);
      ga[t] += 128;
      gb[t] += 128;
    }
    __syncthreads();
#pragma unroll
    for (int kk = 0; kk < 2; kk++) {
      bf16x8 a[4], b[4];
      const int c16 = kk * 4 + (lane >> 4);
#pragma unroll
      for (int i = 0; i < 4; i++) {
        int ra = wm * 64 + i * 16 + (lane & 15);
        a[i] = *(const bf16x8*)(As + ra * 128 + ((c16 ^ (ra & 7)) << 4));
        int rb = wn * 64 + i * 16 + (lane & 15);
        b[i] = *(const bf16x8*)(Bs + rb * 128 + ((c16 ^ (rb & 7)) << 4));
      }
#pragma unroll
      for (int i = 0; i < 4; i++)
#pragma unroll
        for (int j = 0; j < 4; j++)
          acc[i][j] = __builtin_amdgcn_mfma_f32_16x16x32_bf16(a[i], b[j], acc[i][j], 0, 0, 0);
    }
  }

#pragma unroll
  for (int i = 0; i < 4; i++)
#pragma unroll
    for (int j = 0; j < 4; j++)
#pragma unroll
      for (int r = 0; r < 4; r++) {
        int row = bm * 128 + wm * 64 + i * 16 + ((lane >> 4) << 2) + r;
        int col = bn * 128 + wn * 64 + j * 16 + (lane & 15);
        size_t idx = (size_t)row * N + col;
        float v = acc[i][j][r];
        if (EPI == 0) {
          ((__bf16*)Cout)[idx] = (__bf16)v;
        } else if (EPI == 1) {
          ((float*)Cout)[idx] = v + res[idx];
        } else {
          float u = 0.7978845608028654f * (v + 0.044715f * v * v * v);
          ((__bf16*)Cout)[idx] = (__bf16)(0.5f * v * (1.0f + tanhf(u)));
        }
      }
}

// ---------------------------------------------------------------------------
// RoPE tables: cos/sin [2048][64] f32 (cos at [0], sin at +131072 elems).
// ---------------------------------------------------------------------------
__global__ __launch_bounds__(256) void rope_tables(float* __restrict__ tab) {
  const int idx = blockIdx.x * 256 + threadIdx.x;  // 131072
  const int s = idx >> 6, j = idx & 63;
  const float inv = powf(10000.0f, -(float)j / 64.0f);
  const float a = (float)s * inv;
  tab[idx] = cosf(a);
  tab[131072 + idx] = sinf(a);
}

// ---------------------------------------------------------------------------
// RoPE apply + head split: qkv bf16 [B*S][6144] -> q_r,k_r bf16 [B][H][S][128].
// ---------------------------------------------------------------------------
__global__ __launch_bounds__(256) void rope_apply(
    const __bf16* __restrict__ qkv, const float* __restrict__ tab,
    __bf16* __restrict__ qr, __bf16* __restrict__ kr) {
  const int idx = blockIdx.x * 256 + threadIdx.x;  // 4194304
  const int j = idx & 63;
  const int h = (idx >> 6) & 15;
  const int s = (idx >> 10) & 2047;
  const int b = idx >> 21;
  const float c = tab[(s << 6) + j], sn = tab[131072 + (s << 6) + j];
  const size_t qi = ((size_t)(b * 2048 + s)) * 6144 + h * 128 + 2 * j;
  const size_t qo = ((size_t)((b * 16 + h) * 2048 + s)) * 128 + 2 * j;
  {
    float e = (float)qkv[qi], o = (float)qkv[qi + 1];
    qr[qo] = (__bf16)(e * c - o * sn);
    qr[qo + 1] = (__bf16)(o * c + e * sn);
  }
  {
    float e = (float)qkv[qi + 2048], o = (float)qkv[qi + 2048 + 1];
    kr[qo] = (__bf16)(e * c - o * sn);
    kr[qo + 1] = (__bf16)(o * c + e * sn);
  }
}

// ---------------------------------------------------------------------------
// V transpose: qkv v-part [B*S][6144] -> vt bf16 [B][H][128][S].
// ---------------------------------------------------------------------------
__global__ __launch_bounds__(256) void v_transpose(
    const __bf16* __restrict__ qkv, __bf16* __restrict__ vt) {
  __shared__ __bf16 t[32][33];
  const int s0 = blockIdx.x * 32, d0 = blockIdx.y * 32, bh = blockIdx.z;
  const int b = bh >> 4, h = bh & 15;
  const int tx = threadIdx.x, ty = threadIdx.y;  // (32,8)
#pragma unroll
  for (int i = 0; i < 4; i++)
    t[ty + 8 * i][tx] =
        qkv[((size_t)(b * 2048 + s0 + ty + 8 * i)) * 6144 + 4096 + h * 128 + d0 + tx];
  __syncthreads();
#pragma unroll
  for (int i = 0; i < 4; i++)
    vt[((size_t)bh * 128 + d0 + ty + 8 * i) * 2048 + s0 + tx] = t[tx][ty + 8 * i];
}

// ---------------------------------------------------------------------------
// Flash attention v2 (causal). QBLK=128 (8 waves x 16 q-rows), KVBLK=64.
// Grid (8,16,2): block runs q-tiles (15-bx) then (bx) -> uniform 34 KV tiles.
// Double-buffered K[64][128] (16-slot swz) / V^T[128][64] (8-slot swz),
// counted vmcnt(4) prefetch. Softmax: per-lane partial ls (reduced once per
// q-tile), __any-gated deferred-max slow path (shfl-max + rescale only when
// some lane exceeds m+8; exact math, P bounded by 2^8).
// LDS: K 2x16K | V 2x16K | P 8x2K = 81920 B.
// ---------------------------------------------------------------------------
__global__ __launch_bounds__(512) void flash_attn(
    const __bf16* __restrict__ qg, const __bf16* __restrict__ kg,
    const __bf16* __restrict__ vtg, __bf16* __restrict__ og) {
  __shared__ char lds[81920];
  const int tid = threadIdx.x, lane = tid & 63, w = tid >> 6;  // w 0..7
  const int h = blockIdx.y, b = blockIdx.z;
  const int bh = b * 16 + h;
  const __bf16* qb = qg + (size_t)bh * 2048 * 128;
  const char* kbb = (const char*)(kg + (size_t)bh * 2048 * 128);
  const char* vbb = (const char*)(vtg + (size_t)bh * 128 * 2048);
  char* Pw = lds + 65536 + w * 2048;

  // staging: K tile 16KB + V tile 16KB, 512 threads -> 2+2 gload16 each
  const char* gK[2];
  const char* gV[2];
#pragma unroll
  for (int t = 0; t < 2; t++) {
    int gg = t * 512 + tid;           // 0..1023
    int rk = gg >> 4, sk = gg & 15;   // K row 0..63, slot 0..15
    gK[t] = kbb + rk * 256 + ((sk ^ (rk & 15)) << 4);
    int rv = gg >> 3, sv = gg & 7;    // V row 0..127, slot 0..7
    gV[t] = vbb + rv * 4096 + ((sv ^ (rv & 7)) << 4);
  }

  const float SL2E = 0.08838834764831845f * 1.4426950408889634f;  // scale*log2(e)

  auto stageKV = [&](int kt, int buf) {
#pragma unroll
    for (int t = 0; t < 2; t++) {
      int gg = t * 512 + tid;
      gload16(gK[t] + (size_t)kt * 16384, lds + buf * 16384 + gg * 16);
      gload16(gV[t] + (size_t)kt * 128, lds + 32768 + buf * 16384 + gg * 16);
    }
  };

  auto run_qtile = [&](int qt) {
    const int qrow0 = qt * 128 + w * 16;
    bf16x8 qf[4];
#pragma unroll
    for (int c = 0; c < 4; c++) {
      bf16x8 raw = *(const bf16x8*)(qb + (size_t)(qrow0 + (lane & 15)) * 128 +
                                    c * 32 + ((lane >> 4) << 3));
#pragma unroll
      for (int e = 0; e < 8; e++) qf[c][e] = (__bf16)((float)raw[e] * SL2E);
    }
    float m[4], lsp[4];
    f32x4 o[8];
#pragma unroll
    for (int r = 0; r < 4; r++) { m[r] = -__builtin_inff(); lsp[r] = 0.f; }
#pragma unroll
    for (int n = 0; n < 8; n++) o[n] = (f32x4){0.f, 0.f, 0.f, 0.f};

    const int NKT = 2 * qt + 2;
    stageKV(0, 0);

    for (int kt = 0; kt < NKT; kt++) {
      const int cur = kt & 1;
      const char* Ks = lds + cur * 16384;
      const char* Vs = lds + 32768 + cur * 16384;
      if (kt < NKT - 1) {
        stageKV(kt + 1, cur ^ 1);
        asm volatile("s_waitcnt vmcnt(4)" ::: "memory");  // current tile landed
      } else {
        asm volatile("s_waitcnt vmcnt(0)" ::: "memory");
      }
      __builtin_amdgcn_s_barrier();

      // QK^T (log2-domain scores)
      f32x4 s[4];
      __builtin_amdgcn_s_setprio(1);
#pragma unroll
      for (int n = 0; n < 4; n++) {
        s[n] = (f32x4){0.f, 0.f, 0.f, 0.f};
#pragma unroll
        for (int c = 0; c < 4; c++) {
          int krow = n * 16 + (lane & 15);
          int c16 = c * 4 + (lane >> 4);
          bf16x8 kf = *(const bf16x8*)(Ks + krow * 256 + ((c16 ^ (krow & 15)) << 4));
          s[n] = __builtin_amdgcn_mfma_f32_16x16x32_bf16(qf[c], kf, s[n], 0, 0, 0);
        }
      }
      __builtin_amdgcn_s_setprio(0);

      // causal mask (only for tiles that touch this wave's rows)
      if (kt * 64 + 63 > qrow0) {
#pragma unroll
        for (int r = 0; r < 4; r++) {
          const int qrow = qrow0 + ((lane >> 4) << 2) + r;
#pragma unroll
          for (int n = 0; n < 4; n++) {
            int col = kt * 64 + n * 16 + (lane & 15);
            if (col > qrow) s[n][r] = -__builtin_inff();
          }
        }
      }

      // deferred-max: per-lane check, slow path only when some lane exceeds m+8
      float tmx[4];
#pragma unroll
      for (int r = 0; r < 4; r++)
        tmx[r] = fmaxf(fmaxf(s[0][r], s[1][r]), fmaxf(s[2][r], s[3][r]));
      bool hot = (tmx[0] > m[0] + 8.f) | (tmx[1] > m[1] + 8.f) |
                 (tmx[2] > m[2] + 8.f) | (tmx[3] > m[3] + 8.f);
      if (__any(hot)) {
        float fc[4];
#pragma unroll
        for (int r = 0; r < 4; r++) {
          float gmx = tmx[r];
#pragma unroll
          for (int mk = 1; mk < 16; mk <<= 1) gmx = fmaxf(gmx, __shfl_xor(gmx, mk));
          float nm = fmaxf(m[r], gmx);
          fc[r] = __builtin_amdgcn_exp2f(m[r] - nm);
          m[r] = nm;
          lsp[r] *= fc[r];
        }
#pragma unroll
        for (int n = 0; n < 8; n++) {
          o[n][0] *= fc[0]; o[n][1] *= fc[1]; o[n][2] *= fc[2]; o[n][3] *= fc[3];
        }
      }

      float p[4][4];
#pragma unroll
      for (int r = 0; r < 4; r++) {
        float sum = 0.f;
#pragma unroll
        for (int n = 0; n < 4; n++) {
          float pv = __builtin_amdgcn_exp2f(s[n][r] - m[r]);
          p[n][r] = pv;
          sum += pv;
        }
        lsp[r] += sum;  // per-lane partial; reduced once per q-tile
      }

      // P -> per-wave swizzled LDS -> A-fragments
#pragma unroll
      for (int n = 0; n < 4; n++)
#pragma unroll
        for (int r = 0; r < 4; r++) {
          int prow = ((lane >> 4) << 2) + r;
          int col = n * 16 + (lane & 15);
          int ch = col >> 3;
          *(__bf16*)(Pw + prow * 128 + ((ch ^ (prow & 7)) << 4) + ((col & 7) << 1)) =
              (__bf16)p[n][r];
        }

      __builtin_amdgcn_s_setprio(1);
#pragma unroll
      for (int kk = 0; kk < 2; kk++) {
        int prow = lane & 15;
        int pc = kk * 4 + (lane >> 4);
        bf16x8 pf = *(const bf16x8*)(Pw + prow * 128 + ((pc ^ (prow & 7)) << 4));
#pragma unroll
        for (int n = 0; n < 8; n++) {
          int vr = n * 16 + (lane & 15);
          bf16x8 vf = *(const bf16x8*)(Vs + vr * 128 + ((pc ^ (vr & 7)) << 4));
          o[n] = __builtin_amdgcn_mfma_f32_16x16x32_bf16(pf, vf, o[n], 0, 0, 0);
        }
      }
      __builtin_amdgcn_s_setprio(0);
      __builtin_amdgcn_s_barrier();  // all reads of cur done before overwrite
    }

    // final: reduce per-lane partial sums across the 16-lane row group
    float inv[4];
#pragma unroll
    for (int r = 0; r < 4; r++) {
      float ls = lsp[r];
#pragma unroll
      for (int mk = 1; mk < 16; mk <<= 1) ls += __shfl_xor(ls, mk);
      inv[r] = 1.0f / ls;
    }
#pragma unroll
    for (int n = 0; n < 8; n++)
#pragma unroll
      for (int r = 0; r < 4; r++) {
        int qrow = qrow0 + ((lane >> 4) << 2) + r;
        og[(size_t)(b * 2048 + qrow) * 2048 + h * 128 + n * 16 + (lane & 15)] =
            (__bf16)(o[n][r] * inv[r]);
      }
  };

  run_qtile(15 - (int)blockIdx.x);
  run_qtile((int)blockIdx.x);
}

// ---------------------------------------------------------------------------
extern "C" void kernel_launch(void* const* d_in, const int* in_sizes, int n_in,
                              void* d_out, int out_size, void* d_ws, size_t ws_size,
                              hipStream_t stream) {
  const float* x = (const float*)d_in[0];
  const float* w_qkv = (const float*)d_in[1];
  const float* w_out = (const float*)d_in[2];
  const float* w_fc = (const float*)d_in[3];
  const float* w_proj = (const float*)d_in[4];
  const float* g_in = (const float*)d_in[5];
  const float* g_ff = (const float*)d_in[6];
  float* out = (float*)d_out;
  char* ws = (char*)d_ws;

  constexpr size_t O_WQKV = 0;           // bf16 [6144][2048]
  constexpr size_t O_WOUT = 25165824;    // bf16 [2048][2048]
  constexpr size_t O_WFC = 33554432;     // bf16 [4096][2048]
  constexpr size_t O_WPROJ = 50331648;   // bf16 [2048][4096]
  constexpr size_t O_H = 67108864;       // bf16 [4096][2048]
  constexpr size_t O_QKV = 83886080;     // bf16 [4096][6144] (later fcact [4096][4096])
  constexpr size_t O_Q = 134217728;      // bf16 [2][16][2048][128]
  constexpr size_t O_K = 150994944;
  constexpr size_t O_VT = 167772160;     // bf16 [2][16][128][2048]
  constexpr size_t O_TAB = 184549376;    // f32 cos/sin [2][2048][64]
  constexpr size_t O_ATTN = 185597952;   // bf16 [4096][2048]
  constexpr size_t O_X1 = 202375168;     // f32 [4096][2048]

  __bf16* wqkvT = (__bf16*)(ws + O_WQKV);
  __bf16* woutT = (__bf16*)(ws + O_WOUT);
  __bf16* wfcT = (__bf16*)(ws + O_WFC);
  __bf16* wprojT = (__bf16*)(ws + O_WPROJ);
  __bf16* h = (__bf16*)(ws + O_H);
  __bf16* qkv = (__bf16*)(ws + O_QKV);
  __bf16* fcact = (__bf16*)(ws + O_QKV);
  __bf16* qr = (__bf16*)(ws + O_Q);
  __bf16* kr = (__bf16*)(ws + O_K);
  __bf16* vt = (__bf16*)(ws + O_VT);
  float* tab = (float*)(ws + O_TAB);
  __bf16* attn = (__bf16*)(ws + O_ATTN);
  float* x1 = (float*)(ws + O_X1);

  const dim3 tb(32, 8);
  transpose_cvt<<<dim3(6144 / 32, 2048 / 32), tb, 0, stream>>>(w_qkv, wqkvT, 2048, 6144);
  transpose_cvt<<<dim3(2048 / 32, 2048 / 32), tb, 0, stream>>>(w_out, woutT, 2048, 2048);
  transpose_cvt<<<dim3(4096 / 32, 2048 / 32), tb, 0, stream>>>(w_fc, wfcT, 2048, 4096);
  transpose_cvt<<<dim3(2048 / 32, 4096 / 32), tb, 0, stream>>>(w_proj, wprojT, 4096, 2048);

  // h = rmsnorm(x, g_in)
  rmsnorm_kernel<<<4096, 256, 0, stream>>>(x, g_in, h);
  // qkv = h @ w_qkv
  gemm_bt<0><<<dim3(48, 32), 256, 0, stream>>>(h, wqkvT, (void*)qkv, nullptr, 4096, 6144, 2048);
  // rope
  rope_tables<<<512, 256, 0, stream>>>(tab);
  rope_apply<<<16384, 256, 0, stream>>>(qkv, tab, qr, kr);
  v_transpose<<<dim3(64, 4, 32), tb, 0, stream>>>(qkv, vt);
  // attention (QBLK=128, balanced pairs)
  flash_attn<<<dim3(8, 16, 2), 512, 0, stream>>>(qr, kr, vt, attn);
  // x1 = x + attn @ w_out
  gemm_bt<1><<<dim3(16, 32), 256, 0, stream>>>(attn, woutT, (void*)x1, x, 4096, 2048, 2048);
  // h2 = rmsnorm(x1, g_ff)
  rmsnorm_kernel<<<4096, 256, 0, stream>>>(x1, g_ff, h);
  // fcact = gelu(h2 @ w_fc)
  gemm_bt<2><<<dim3(32, 32), 256, 0, stream>>>(h, wfcT, (void*)fcact, nullptr, 4096, 4096, 2048);
  // out = x1 + fcact @ w_proj
  gemm_bt<1><<<dim3(16, 32), 256, 0, stream>>>(fcact, wprojT, (void*)out, x1, 4096, 2048, 4096);
}

// Round 5
// 518.099 us; speedup vs baseline: 1.0811x; 1.0055x over previous
//
#include <hip/hip_runtime.h>
#include <math.h>

typedef __bf16 bf16x8 __attribute__((ext_vector_type(8)));
typedef float  f32x4  __attribute__((ext_vector_type(4)));

#define DEV __device__ __forceinline__

DEV void gload16(const void* g, void* l) {
  __builtin_amdgcn_global_load_lds(
      (const __attribute__((address_space(1))) void*)g,
      (__attribute__((address_space(3))) void*)l, 16, 0, 0);
}

// ---------------------------------------------------------------------------
// Weight f32 [R][C] -> bf16 [C][R] (transposed) so GEMMs take B^T row-major.
// ---------------------------------------------------------------------------
__global__ __launch_bounds__(256) void transpose_cvt(
    const float* __restrict__ in, __bf16* __restrict__ outT, int R, int C) {
  __shared__ float t[32][33];
  const int c0 = blockIdx.x * 32, r0 = blockIdx.y * 32;
  const int tx = threadIdx.x, ty = threadIdx.y;  // (32,8)
#pragma unroll
  for (int i = 0; i < 4; i++)
    t[ty + 8 * i][tx] = in[(size_t)(r0 + ty + 8 * i) * C + c0 + tx];
  __syncthreads();
#pragma unroll
  for (int i = 0; i < 4; i++)
    outT[(size_t)(c0 + ty + 8 * i) * R + r0 + tx] = (__bf16)t[tx][ty + 8 * i];
}

// ---------------------------------------------------------------------------
// RMSNorm row kernel: f32 [rows][2048] -> bf16, 1 block/row, 8 elems/thread.
// ---------------------------------------------------------------------------
__global__ __launch_bounds__(256) void rmsnorm_kernel(
    const float* __restrict__ x, const float* __restrict__ g, __bf16* __restrict__ out) {
  const int r = blockIdx.x, t = threadIdx.x;
  const float4* xr = (const float4*)(x + (size_t)r * 2048);
  float4 a = xr[2 * t], b = xr[2 * t + 1];
  float ss = a.x * a.x + a.y * a.y + a.z * a.z + a.w * a.w +
             b.x * b.x + b.y * b.y + b.z * b.z + b.w * b.w;
#pragma unroll
  for (int mk = 1; mk < 64; mk <<= 1) ss += __shfl_xor(ss, mk);
  __shared__ float red[4];
  if ((t & 63) == 0) red[t >> 6] = ss;
  __syncthreads();
  const float sc = rsqrtf((red[0] + red[1] + red[2] + red[3]) * (1.0f / 2048.0f) + 1e-6f);
  const float4* gr = (const float4*)g;
  float4 ga = gr[2 * t], gb = gr[2 * t + 1];
  bf16x8 ov;
  ov[0] = (__bf16)(a.x * sc * ga.x); ov[1] = (__bf16)(a.y * sc * ga.y);
  ov[2] = (__bf16)(a.z * sc * ga.z); ov[3] = (__bf16)(a.w * sc * ga.w);
  ov[4] = (__bf16)(b.x * sc * gb.x); ov[5] = (__bf16)(b.y * sc * gb.y);
  ov[6] = (__bf16)(b.z * sc * gb.z); ov[7] = (__bf16)(b.w * sc * gb.w);
  *(bf16x8*)(out + (size_t)r * 2048 + t * 8) = ov;
}

// ---------------------------------------------------------------------------
// GEMM 128x128 (m97 structure, 895 TF) — used for N=2048 outputs (wout/proj).
// EPI: 0 = bf16 store, 1 = f32 store + residual, 2 = gelu -> bf16.
// ---------------------------------------------------------------------------
template <int EPI>
__global__ __launch_bounds__(256) void gemm_bt(
    const __bf16* __restrict__ A, const __bf16* __restrict__ BT,
    void* __restrict__ Cout, const float* __restrict__ res, int M, int N, int K) {
  __shared__ char lds[32768];
  char* As = lds;
  char* Bs = lds + 16384;
  const int tid = threadIdx.x;
  const int lane = tid & 63;
  const int bn = blockIdx.x, bm = blockIdx.y;
  const int wm = tid >> 7, wn = (tid >> 6) & 1;

  f32x4 acc[4][4];
#pragma unroll
  for (int i = 0; i < 4; i++)
#pragma unroll
    for (int j = 0; j < 4; j++) acc[i][j] = (f32x4){0.f, 0.f, 0.f, 0.f};

  const size_t strideA = (size_t)K * 2;
  const char* ga[4];
  const char* gb[4];
#pragma unroll
  for (int t = 0; t < 4; t++) {
    int gg = t * 256 + tid;
    int row = gg >> 3, slot = gg & 7;
    ga[t] = (const char*)A + (size_t)(bm * 128 + row) * strideA + ((slot ^ (row & 7)) << 4);
    gb[t] = (const char*)BT + (size_t)(bn * 128 + row) * strideA + ((slot ^ (row & 7)) << 4);
  }

  for (int k0 = 0; k0 < K; k0 += 64) {
    __syncthreads();
#pragma unroll
    for (int t = 0; t < 4; t++) {
      int gg = t * 256 + tid;
      gload16(ga[t], As + gg * 16);
      gload16(gb[t], Bs + gg * 16);
      ga[t] += 128;
      gb[t] += 128;
    }
    __syncthreads();
#pragma unroll
    for (int kk = 0; kk < 2; kk++) {
      bf16x8 a[4], b[4];
      const int c16 = kk * 4 + (lane >> 4);
#pragma unroll
      for (int i = 0; i < 4; i++) {
        int ra = wm * 64 + i * 16 + (lane & 15);
        a[i] = *(const bf16x8*)(As + ra * 128 + ((c16 ^ (ra & 7)) << 4));
        int rb = wn * 64 + i * 16 + (lane & 15);
        b[i] = *(const bf16x8*)(Bs + rb * 128 + ((c16 ^ (rb & 7)) << 4));
      }
#pragma unroll
      for (int i = 0; i < 4; i++)
#pragma unroll
        for (int j = 0; j < 4; j++)
          acc[i][j] = __builtin_amdgcn_mfma_f32_16x16x32_bf16(a[i], b[j], acc[i][j], 0, 0, 0);
    }
  }

#pragma unroll
  for (int i = 0; i < 4; i++)
#pragma unroll
    for (int j = 0; j < 4; j++)
#pragma unroll
      for (int r = 0; r < 4; r++) {
        int row = bm * 128 + wm * 64 + i * 16 + ((lane >> 4) << 2) + r;
        int col = bn * 128 + wn * 64 + j * 16 + (lane & 15);
        size_t idx = (size_t)row * N + col;
        float v = acc[i][j][r];
        if (EPI == 0) {
          ((__bf16*)Cout)[idx] = (__bf16)v;
        } else if (EPI == 1) {
          ((float*)Cout)[idx] = v + res[idx];
        } else {
          float u = 0.7978845608028654f * (v + 0.044715f * v * v * v);
          ((__bf16*)Cout)[idx] = (__bf16)(0.5f * v * (1.0f + tanhf(u)));
        }
      }
}

// ---------------------------------------------------------------------------
// GEMM 256x256 8-phase (m201 template, T2+T3+T4+T5). BK=64, 8 waves (2Mx4N,
// each 128x64). LDS 128 KiB = {A,B} x 2buf x 2half x (128x64 bf16), XOR-swz.
// Each phase: {ds_read subtile || stage 1 half-tile -> barrier -> MFMA(prio)
// -> barrier}; counted waits vmcnt(4)@ph4, vmcnt(6)@ph8 ONLY (never 0).
// Stage schedule (iter tiles e=2it buf0, o=e+1 buf1; e'=e+2, o'=e+3 clamped):
//  ph3:B0e' ph4:B1e' ph5:A0e' ph6:A1e' ph7:B0o' ph8:B1o'+A0o'+A1o'
// Derived drain proof: every half-tile read at phase P was staged >=4 halves
// before the wait preceding P -> drained. Slots staged only after their
// block-wide last read (B halves after ph2/ph6, A halves after ph3/ph7).
// ---------------------------------------------------------------------------
#define MMQ(IB, JB, AR, BR)                                                   \
  __builtin_amdgcn_s_setprio(1);                                              \
  _Pragma("unroll") for (int i = 0; i < 4; i++)                               \
      _Pragma("unroll") for (int j = 0; j < 2; j++)                           \
          _Pragma("unroll") for (int kk = 0; kk < 2; kk++)                    \
              acc[(IB)*4 + i][(JB)*2 + j] =                                   \
      __builtin_amdgcn_mfma_f32_16x16x32_bf16(                                \
          AR[i][kk], BR[j][kk], acc[(IB)*4 + i][(JB)*2 + j], 0, 0, 0);        \
  __builtin_amdgcn_s_setprio(0);

template <int EPI>
__global__ __launch_bounds__(512, 2) void gemm256(
    const __bf16* __restrict__ A, const __bf16* __restrict__ BT,
    void* __restrict__ Cout, const float* __restrict__ res, int M, int N, int K) {
  __shared__ char lds[131072];
  const int tid = threadIdx.x, lane = tid & 63, w = tid >> 6;
  const int wm = w >> 2, wn = w & 3;
  const int bn = blockIdx.x, bm = blockIdx.y;

  f32x4 acc[8][4];
#pragma unroll
  for (int i = 0; i < 8; i++)
#pragma unroll
    for (int j = 0; j < 4; j++) acc[i][j] = (f32x4){0.f, 0.f, 0.f, 0.f};

  const size_t strideA = (size_t)K * 2;
  const int r0 = tid >> 3, s0 = tid & 7;
  const int r1 = r0 + 64;
  const char* Ab0 = (const char*)A + (size_t)(bm * 256) * strideA;
  const char* Bb0 = (const char*)BT + (size_t)(bn * 256) * strideA;

  auto stage = [&](int isB, int h, int kt, int buf) {
    const char* g = (isB ? Bb0 : Ab0) + (size_t)(h * 128) * strideA + (size_t)kt * 128;
    char* d = lds + isB * 65536 + buf * 32768 + h * 16384;
    gload16(g + (size_t)r0 * strideA + ((s0 ^ (r0 & 7)) << 4), d + tid * 16);
    gload16(g + (size_t)r1 * strideA + ((s0 ^ (r1 & 7)) << 4), d + (tid + 512) * 16);
  };
  auto ldA = [&](bf16x8 (&a)[4][2], int buf, int bank) {
    const char* base = lds + buf * 32768 + wm * 16384;
#pragma unroll
    for (int i = 0; i < 4; i++)
#pragma unroll
      for (int kk = 0; kk < 2; kk++) {
        int rl = bank * 64 + i * 16 + (lane & 15);
        int c16 = kk * 4 + (lane >> 4);
        a[i][kk] = *(const bf16x8*)(base + rl * 128 + ((c16 ^ (rl & 7)) << 4));
      }
  };
  auto ldB = [&](bf16x8 (&b)[2][2], int buf, int jb) {
    const char* base = lds + 65536 + buf * 32768 + (wn >> 1) * 16384;
#pragma unroll
    for (int j = 0; j < 2; j++)
#pragma unroll
      for (int kk = 0; kk < 2; kk++) {
        int rl = (wn & 1) * 64 + jb * 32 + j * 16 + (lane & 15);
        int c16 = kk * 4 + (lane >> 4);
        b[j][kk] = *(const bf16x8*)(base + rl * 128 + ((c16 ^ (rl & 7)) << 4));
      }
  };

  const int NT = K >> 6;  // 64-wide K-tiles (even count assumed)
  // prologue: tiles 0 (buf0) and 1 (buf1); survivors after wait = last 3 halves
  stage(1, 0, 0, 0); stage(1, 1, 0, 0); stage(0, 0, 0, 0); stage(0, 1, 0, 0);
  stage(1, 0, 1, 1); stage(1, 1, 1, 1); stage(0, 0, 1, 1); stage(0, 1, 1, 1);
  asm volatile("s_waitcnt vmcnt(6)" ::: "memory");
  __builtin_amdgcn_s_barrier();

  bf16x8 a[4][2], b0[2][2], b1[2][2];
  for (int it = 0; it < (NT >> 1); ++it) {
    const int e = 2 * it;
    const int ep = (e + 2 < NT) ? e + 2 : NT - 1;
    const int op = (e + 3 < NT) ? e + 3 : NT - 1;
    // ph1 — tile e quadrant (0,0)
    ldA(a, 0, 0); ldB(b0, 0, 0);
    __builtin_amdgcn_s_barrier();
    MMQ(0, 0, a, b0);
    __builtin_amdgcn_s_barrier();
    // ph2 — (0,1)
    ldB(b1, 0, 1);
    __builtin_amdgcn_s_barrier();
    MMQ(0, 1, a, b1);
    __builtin_amdgcn_s_barrier();
    // ph3 — (1,1)
    ldA(a, 0, 1); stage(1, 0, ep, 0);
    __builtin_amdgcn_s_barrier();
    MMQ(1, 1, a, b1);
    __builtin_amdgcn_s_barrier();
    // ph4 — (1,0)
    stage(1, 1, ep, 0);
    asm volatile("s_waitcnt vmcnt(4)" ::: "memory");
    __builtin_amdgcn_s_barrier();
    MMQ(1, 0, a, b0);
    __builtin_amdgcn_s_barrier();
    // ph5 — tile o quadrant (0,0)
    ldA(a, 1, 0); ldB(b0, 1, 0); stage(0, 0, ep, 0);
    __builtin_amdgcn_s_barrier();
    MMQ(0, 0, a, b0);
    __builtin_amdgcn_s_barrier();
    // ph6 — (0,1)
    ldB(b1, 1, 1); stage(0, 1, ep, 0);
    __builtin_amdgcn_s_barrier();
    MMQ(0, 1, a, b1);
    __builtin_amdgcn_s_barrier();
    // ph7 — (1,1)
    ldA(a, 1, 1); stage(1, 0, op, 1);
    __builtin_amdgcn_s_barrier();
    MMQ(1, 1, a, b1);
    __builtin_amdgcn_s_barrier();
    // ph8 — (1,0)
    stage(1, 1, op, 1); stage(0, 0, op, 1); stage(0, 1, op, 1);
    asm volatile("s_waitcnt vmcnt(6)" ::: "memory");
    __builtin_amdgcn_s_barrier();
    MMQ(1, 0, a, b0);
    __builtin_amdgcn_s_barrier();
  }
  asm volatile("s_waitcnt vmcnt(0)" ::: "memory");

#pragma unroll
  for (int i = 0; i < 8; i++)
#pragma unroll
    for (int j = 0; j < 4; j++)
#pragma unroll
      for (int r = 0; r < 4; r++) {
        int row = bm * 256 + wm * 128 + i * 16 + ((lane >> 4) << 2) + r;
        int col = bn * 256 + wn * 64 + j * 16 + (lane & 15);
        size_t idx = (size_t)row * N + col;
        float v = acc[i][j][r];
        if (EPI == 0) {
          ((__bf16*)Cout)[idx] = (__bf16)v;
        } else if (EPI == 1) {
          ((float*)Cout)[idx] = v + res[idx];
        } else {
          float u = 0.7978845608028654f * (v + 0.044715f * v * v * v);
          ((__bf16*)Cout)[idx] = (__bf16)(0.5f * v * (1.0f + tanhf(u)));
        }
      }
}

// ---------------------------------------------------------------------------
// RoPE tables: cos/sin [2048][64] f32 (cos at [0], sin at +131072 elems).
// ---------------------------------------------------------------------------
__global__ __launch_bounds__(256) void rope_tables(float* __restrict__ tab) {
  const int idx = blockIdx.x * 256 + threadIdx.x;  // 131072
  const int s = idx >> 6, j = idx & 63;
  const float inv = powf(10000.0f, -(float)j / 64.0f);
  const float a = (float)s * inv;
  tab[idx] = cosf(a);
  tab[131072 + idx] = sinf(a);
}

// ---------------------------------------------------------------------------
// RoPE apply + head split: qkv bf16 [B*S][6144] -> q_r,k_r bf16 [B][H][S][128].
// ---------------------------------------------------------------------------
__global__ __launch_bounds__(256) void rope_apply(
    const __bf16* __restrict__ qkv, const float* __restrict__ tab,
    __bf16* __restrict__ qr, __bf16* __restrict__ kr) {
  const int idx = blockIdx.x * 256 + threadIdx.x;  // 4194304
  const int j = idx & 63;
  const int h = (idx >> 6) & 15;
  const int s = (idx >> 10) & 2047;
  const int b = idx >> 21;
  const float c = tab[(s << 6) + j], sn = tab[131072 + (s << 6) + j];
  const size_t qi = ((size_t)(b * 2048 + s)) * 6144 + h * 128 + 2 * j;
  const size_t qo = ((size_t)((b * 16 + h) * 2048 + s)) * 128 + 2 * j;
  {
    float e = (float)qkv[qi], o = (float)qkv[qi + 1];
    qr[qo] = (__bf16)(e * c - o * sn);
    qr[qo + 1] = (__bf16)(o * c + e * sn);
  }
  {
    float e = (float)qkv[qi + 2048], o = (float)qkv[qi + 2048 + 1];
    kr[qo] = (__bf16)(e * c - o * sn);
    kr[qo + 1] = (__bf16)(o * c + e * sn);
  }
}

// ---------------------------------------------------------------------------
// V transpose: qkv v-part [B*S][6144] -> vt bf16 [B][H][128][S].
// ---------------------------------------------------------------------------
__global__ __launch_bounds__(256) void v_transpose(
    const __bf16* __restrict__ qkv, __bf16* __restrict__ vt) {
  __shared__ __bf16 t[32][33];
  const int s0 = blockIdx.x * 32, d0 = blockIdx.y * 32, bh = blockIdx.z;
  const int b = bh >> 4, h = bh & 15;
  const int tx = threadIdx.x, ty = threadIdx.y;  // (32,8)
#pragma unroll
  for (int i = 0; i < 4; i++)
    t[ty + 8 * i][tx] =
        qkv[((size_t)(b * 2048 + s0 + ty + 8 * i)) * 6144 + 4096 + h * 128 + d0 + tx];
  __syncthreads();
#pragma unroll
  for (int i = 0; i < 4; i++)
    vt[((size_t)bh * 128 + d0 + ty + 8 * i) * 2048 + s0 + tx] = t[tx][ty + 8 * i];
}

// ---------------------------------------------------------------------------
// Flash attention v2 (causal). QBLK=128 (8 waves x 16 q-rows), KVBLK=64.
// (unchanged from R4 — verified)
// ---------------------------------------------------------------------------
__global__ __launch_bounds__(512) void flash_attn(
    const __bf16* __restrict__ qg, const __bf16* __restrict__ kg,
    const __bf16* __restrict__ vtg, __bf16* __restrict__ og) {
  __shared__ char lds[81920];
  const int tid = threadIdx.x, lane = tid & 63, w = tid >> 6;  // w 0..7
  const int h = blockIdx.y, b = blockIdx.z;
  const int bh = b * 16 + h;
  const __bf16* qb = qg + (size_t)bh * 2048 * 128;
  const char* kbb = (const char*)(kg + (size_t)bh * 2048 * 128);
  const char* vbb = (const char*)(vtg + (size_t)bh * 128 * 2048);
  char* Pw = lds + 65536 + w * 2048;

  const char* gK[2];
  const char* gV[2];
#pragma unroll
  for (int t = 0; t < 2; t++) {
    int gg = t * 512 + tid;           // 0..1023
    int rk = gg >> 4, sk = gg & 15;   // K row 0..63, slot 0..15
    gK[t] = kbb + rk * 256 + ((sk ^ (rk & 15)) << 4);
    int rv = gg >> 3, sv = gg & 7;    // V row 0..127, slot 0..7
    gV[t] = vbb + rv * 4096 + ((sv ^ (rv & 7)) << 4);
  }

  const float SL2E = 0.08838834764831845f * 1.4426950408889634f;  // scale*log2(e)

  auto stageKV = [&](int kt, int buf) {
#pragma unroll
    for (int t = 0; t < 2; t++) {
      int gg = t * 512 + tid;
      gload16(gK[t] + (size_t)kt * 16384, lds + buf * 16384 + gg * 16);
      gload16(gV[t] + (size_t)kt * 128, lds + 32768 + buf * 16384 + gg * 16);
    }
  };

  auto run_qtile = [&](int qt) {
    const int qrow0 = qt * 128 + w * 16;
    bf16x8 qf[4];
#pragma unroll
    for (int c = 0; c < 4; c++) {
      bf16x8 raw = *(const bf16x8*)(qb + (size_t)(qrow0 + (lane & 15)) * 128 +
                                    c * 32 + ((lane >> 4) << 3));
#pragma unroll
      for (int e = 0; e < 8; e++) qf[c][e] = (__bf16)((float)raw[e] * SL2E);
    }
    float m[4], lsp[4];
    f32x4 o[8];
#pragma unroll
    for (int r = 0; r < 4; r++) { m[r] = -__builtin_inff(); lsp[r] = 0.f; }
#pragma unroll
    for (int n = 0; n < 8; n++) o[n] = (f32x4){0.f, 0.f, 0.f, 0.f};

    const int NKT = 2 * qt + 2;
    stageKV(0, 0);

    for (int kt = 0; kt < NKT; kt++) {
      const int cur = kt & 1;
      const char* Ks = lds + cur * 16384;
      const char* Vs = lds + 32768 + cur * 16384;
      if (kt < NKT - 1) {
        stageKV(kt + 1, cur ^ 1);
        asm volatile("s_waitcnt vmcnt(4)" ::: "memory");  // current tile landed
      } else {
        asm volatile("s_waitcnt vmcnt(0)" ::: "memory");
      }
      __builtin_amdgcn_s_barrier();

      // QK^T (log2-domain scores)
      f32x4 s[4];
      __builtin_amdgcn_s_setprio(1);
#pragma unroll
      for (int n = 0; n < 4; n++) {
        s[n] = (f32x4){0.f, 0.f, 0.f, 0.f};
#pragma unroll
        for (int c = 0; c < 4; c++) {
          int krow = n * 16 + (lane & 15);
          int c16 = c * 4 + (lane >> 4);
          bf16x8 kf = *(const bf16x8*)(Ks + krow * 256 + ((c16 ^ (krow & 15)) << 4));
          s[n] = __builtin_amdgcn_mfma_f32_16x16x32_bf16(qf[c], kf, s[n], 0, 0, 0);
        }
      }
      __builtin_amdgcn_s_setprio(0);

      // causal mask (only for tiles that touch this wave's rows)
      if (kt * 64 + 63 > qrow0) {
#pragma unroll
        for (int r = 0; r < 4; r++) {
          const int qrow = qrow0 + ((lane >> 4) << 2) + r;
#pragma unroll
          for (int n = 0; n < 4; n++) {
            int col = kt * 64 + n * 16 + (lane & 15);
            if (col > qrow) s[n][r] = -__builtin_inff();
          }
        }
      }

      // deferred-max: per-lane check, slow path only when some lane exceeds m+8
      float tmx[4];
#pragma unroll
      for (int r = 0; r < 4; r++)
        tmx[r] = fmaxf(fmaxf(s[0][r], s[1][r]), fmaxf(s[2][r], s[3][r]));
      bool hot = (tmx[0] > m[0] + 8.f) | (tmx[1] > m[1] + 8.f) |
                 (tmx[2] > m[2] + 8.f) | (tmx[3] > m[3] + 8.f);
      if (__any(hot)) {
        float fc[4];
#pragma unroll
        for (int r = 0; r < 4; r++) {
          float gmx = tmx[r];
#pragma unroll
          for (int mk = 1; mk < 16; mk <<= 1) gmx = fmaxf(gmx, __shfl_xor(gmx, mk));
          float nm = fmaxf(m[r], gmx);
          fc[r] = __builtin_amdgcn_exp2f(m[r] - nm);
          m[r] = nm;
          lsp[r] *= fc[r];
        }
#pragma unroll
        for (int n = 0; n < 8; n++) {
          o[n][0] *= fc[0]; o[n][1] *= fc[1]; o[n][2] *= fc[2]; o[n][3] *= fc[3];
        }
      }

      float p[4][4];
#pragma unroll
      for (int r = 0; r < 4; r++) {
        float sum = 0.f;
#pragma unroll
        for (int n = 0; n < 4; n++) {
          float pv = __builtin_amdgcn_exp2f(s[n][r] - m[r]);
          p[n][r] = pv;
          sum += pv;
        }
        lsp[r] += sum;  // per-lane partial; reduced once per q-tile
      }

      // P -> per-wave swizzled LDS -> A-fragments
#pragma unroll
      for (int n = 0; n < 4; n++)
#pragma unroll
        for (int r = 0; r < 4; r++) {
          int prow = ((lane >> 4) << 2) + r;
          int col = n * 16 + (lane & 15);
          int ch = col >> 3;
          *(__bf16*)(Pw + prow * 128 + ((ch ^ (prow & 7)) << 4) + ((col & 7) << 1)) =
              (__bf16)p[n][r];
        }

      __builtin_amdgcn_s_setprio(1);
#pragma unroll
      for (int kk = 0; kk < 2; kk++) {
        int prow = lane & 15;
        int pc = kk * 4 + (lane >> 4);
        bf16x8 pf = *(const bf16x8*)(Pw + prow * 128 + ((pc ^ (prow & 7)) << 4));
#pragma unroll
        for (int n = 0; n < 8; n++) {
          int vr = n * 16 + (lane & 15);
          bf16x8 vf = *(const bf16x8*)(Vs + vr * 128 + ((pc ^ (vr & 7)) << 4));
          o[n] = __builtin_amdgcn_mfma_f32_16x16x32_bf16(pf, vf, o[n], 0, 0, 0);
        }
      }
      __builtin_amdgcn_s_setprio(0);
      __builtin_amdgcn_s_barrier();  // all reads of cur done before overwrite
    }

    // final: reduce per-lane partial sums across the 16-lane row group
    float inv[4];
#pragma unroll
    for (int r = 0; r < 4; r++) {
      float ls = lsp[r];
#pragma unroll
      for (int mk = 1; mk < 16; mk <<= 1) ls += __shfl_xor(ls, mk);
      inv[r] = 1.0f / ls;
    }
#pragma unroll
    for (int n = 0; n < 8; n++)
#pragma unroll
      for (int r = 0; r < 4; r++) {
        int qrow = qrow0 + ((lane >> 4) << 2) + r;
        og[(size_t)(b * 2048 + qrow) * 2048 + h * 128 + n * 16 + (lane & 15)] =
            (__bf16)(o[n][r] * inv[r]);
      }
  };

  run_qtile(15 - (int)blockIdx.x);
  run_qtile((int)blockIdx.x);
}

// ---------------------------------------------------------------------------
extern "C" void kernel_launch(void* const* d_in, const int* in_sizes, int n_in,
                              void* d_out, int out_size, void* d_ws, size_t ws_size,
                              hipStream_t stream) {
  const float* x = (const float*)d_in[0];
  const float* w_qkv = (const float*)d_in[1];
  const float* w_out = (const float*)d_in[2];
  const float* w_fc = (const float*)d_in[3];
  const float* w_proj = (const float*)d_in[4];
  const float* g_in = (const float*)d_in[5];
  const float* g_ff = (const float*)d_in[6];
  float* out = (float*)d_out;
  char* ws = (char*)d_ws;

  constexpr size_t O_WQKV = 0;           // bf16 [6144][2048]
  constexpr size_t O_WOUT = 25165824;    // bf16 [2048][2048]
  constexpr size_t O_WFC = 33554432;     // bf16 [4096][2048]
  constexpr size_t O_WPROJ = 50331648;   // bf16 [2048][4096]
  constexpr size_t O_H = 67108864;       // bf16 [4096][2048]
  constexpr size_t O_QKV = 83886080;     // bf16 [4096][6144] (later fcact [4096][4096])
  constexpr size_t O_Q = 134217728;      // bf16 [2][16][2048][128]
  constexpr size_t O_K = 150994944;
  constexpr size_t O_VT = 167772160;     // bf16 [2][16][128][2048]
  constexpr size_t O_TAB = 184549376;    // f32 cos/sin [2][2048][64]
  constexpr size_t O_ATTN = 185597952;   // bf16 [4096][2048]
  constexpr size_t O_X1 = 202375168;     // f32 [4096][2048]

  __bf16* wqkvT = (__bf16*)(ws + O_WQKV);
  __bf16* woutT = (__bf16*)(ws + O_WOUT);
  __bf16* wfcT = (__bf16*)(ws + O_WFC);
  __bf16* wprojT = (__bf16*)(ws + O_WPROJ);
  __bf16* h = (__bf16*)(ws + O_H);
  __bf16* qkv = (__bf16*)(ws + O_QKV);
  __bf16* fcact = (__bf16*)(ws + O_QKV);
  __bf16* qr = (__bf16*)(ws + O_Q);
  __bf16* kr = (__bf16*)(ws + O_K);
  __bf16* vt = (__bf16*)(ws + O_VT);
  float* tab = (float*)(ws + O_TAB);
  __bf16* attn = (__bf16*)(ws + O_ATTN);
  float* x1 = (float*)(ws + O_X1);

  const dim3 tb(32, 8);
  transpose_cvt<<<dim3(6144 / 32, 2048 / 32), tb, 0, stream>>>(w_qkv, wqkvT, 2048, 6144);
  transpose_cvt<<<dim3(2048 / 32, 2048 / 32), tb, 0, stream>>>(w_out, woutT, 2048, 2048);
  transpose_cvt<<<dim3(4096 / 32, 2048 / 32), tb, 0, stream>>>(w_fc, wfcT, 2048, 4096);
  transpose_cvt<<<dim3(2048 / 32, 4096 / 32), tb, 0, stream>>>(w_proj, wprojT, 4096, 2048);

  // h = rmsnorm(x, g_in)
  rmsnorm_kernel<<<4096, 256, 0, stream>>>(x, g_in, h);
  // qkv = h @ w_qkv  (256^2 8-phase)
  gemm256<0><<<dim3(24, 16), 512, 0, stream>>>(h, wqkvT, (void*)qkv, nullptr, 4096, 6144, 2048);
  // rope
  rope_tables<<<512, 256, 0, stream>>>(tab);
  rope_apply<<<16384, 256, 0, stream>>>(qkv, tab, qr, kr);
  v_transpose<<<dim3(64, 4, 32), tb, 0, stream>>>(qkv, vt);
  // attention (QBLK=128, balanced pairs)
  flash_attn<<<dim3(8, 16, 2), 512, 0, stream>>>(qr, kr, vt, attn);
  // x1 = x + attn @ w_out
  gemm_bt<1><<<dim3(16, 32), 256, 0, stream>>>(attn, woutT, (void*)x1, x, 4096, 2048, 2048);
  // h2 = rmsnorm(x1, g_ff)
  rmsnorm_kernel<<<4096, 256, 0, stream>>>(x1, g_ff, h);
  // fcact = gelu(h2 @ w_fc)  (256^2 8-phase)
  gemm256<2><<<dim3(16, 16), 512, 0, stream>>>(h, wfcT, (void*)fcact, nullptr, 4096, 4096, 2048);
  // out = x1 + fcact @ w_proj
  gemm_bt<1><<<dim3(16, 32), 256, 0, stream>>>(fcact, wprojT, (void*)out, x1, 4096, 2048, 4096);
}

// Round 6
// 488.643 us; speedup vs baseline: 1.1463x; 1.0603x over previous
//
#include <hip/hip_runtime.h>
#include <math.h>

typedef __bf16 bf16x8 __attribute__((ext_vector_type(8)));
typedef float  f32x4  __attribute__((ext_vector_type(4)));

#define DEV __device__ __forceinline__

DEV void gload16(const void* g, void* l) {
  __builtin_amdgcn_global_load_lds(
      (const __attribute__((address_space(1))) void*)g,
      (__attribute__((address_space(3))) void*)l, 16, 0, 0);
}

// ---------------------------------------------------------------------------
// Weight f32 [R][C] -> bf16 [C][R], 64x64 tiles, float4 reads / bf16x8 writes.
// LDS pad 65: load-phase banks (r+4cf+q)%32 and gather banks (8r8+k+c)%32 are
// both <=2-way (free). All R,C here are multiples of 64.
// ---------------------------------------------------------------------------
__global__ __launch_bounds__(256) void transpose_cvt(
    const float* __restrict__ in, __bf16* __restrict__ outT, int R, int C) {
  __shared__ float t[64][65];
  const int c0 = blockIdx.x * 64, r0 = blockIdx.y * 64;
  const int tid = threadIdx.x;
#pragma unroll
  for (int i = 0; i < 4; i++) {
    int r = (tid >> 4) + i * 16;
    int cf = tid & 15;
    float4 v = *(const float4*)(in + (size_t)(r0 + r) * C + c0 + cf * 4);
    t[r][cf * 4 + 0] = v.x; t[r][cf * 4 + 1] = v.y;
    t[r][cf * 4 + 2] = v.z; t[r][cf * 4 + 3] = v.w;
  }
  __syncthreads();
#pragma unroll
  for (int i = 0; i < 2; i++) {
    int c = (tid >> 3) + i * 32;
    int r8 = tid & 7;
    bf16x8 ov;
#pragma unroll
    for (int k = 0; k < 8; k++) ov[k] = (__bf16)t[r8 * 8 + k][c];
    *(bf16x8*)(outT + (size_t)(c0 + c) * R + r0 + r8 * 8) = ov;
  }
}

// ---------------------------------------------------------------------------
// RMSNorm row kernel: f32 [rows][2048] -> bf16, 1 block/row, 8 elems/thread.
// ---------------------------------------------------------------------------
__global__ __launch_bounds__(256) void rmsnorm_kernel(
    const float* __restrict__ x, const float* __restrict__ g, __bf16* __restrict__ out) {
  const int r = blockIdx.x, t = threadIdx.x;
  const float4* xr = (const float4*)(x + (size_t)r * 2048);
  float4 a = xr[2 * t], b = xr[2 * t + 1];
  float ss = a.x * a.x + a.y * a.y + a.z * a.z + a.w * a.w +
             b.x * b.x + b.y * b.y + b.z * b.z + b.w * b.w;
#pragma unroll
  for (int mk = 1; mk < 64; mk <<= 1) ss += __shfl_xor(ss, mk);
  __shared__ float red[4];
  if ((t & 63) == 0) red[t >> 6] = ss;
  __syncthreads();
  const float sc = rsqrtf((red[0] + red[1] + red[2] + red[3]) * (1.0f / 2048.0f) + 1e-6f);
  const float4* gr = (const float4*)g;
  float4 ga = gr[2 * t], gb = gr[2 * t + 1];
  bf16x8 ov;
  ov[0] = (__bf16)(a.x * sc * ga.x); ov[1] = (__bf16)(a.y * sc * ga.y);
  ov[2] = (__bf16)(a.z * sc * ga.z); ov[3] = (__bf16)(a.w * sc * ga.w);
  ov[4] = (__bf16)(b.x * sc * gb.x); ov[5] = (__bf16)(b.y * sc * gb.y);
  ov[6] = (__bf16)(b.z * sc * gb.z); ov[7] = (__bf16)(b.w * sc * gb.w);
  *(bf16x8*)(out + (size_t)r * 2048 + t * 8) = ov;
}

// ---------------------------------------------------------------------------
// GEMM 128x128 (m97 structure, 895 TF) — qkv / wout / proj.
// EPI: 0 = bf16 store, 1 = f32 store + residual, 2 = gelu -> bf16.
// ---------------------------------------------------------------------------
template <int EPI>
__global__ __launch_bounds__(256) void gemm_bt(
    const __bf16* __restrict__ A, const __bf16* __restrict__ BT,
    void* __restrict__ Cout, const float* __restrict__ res, int M, int N, int K) {
  __shared__ char lds[32768];
  char* As = lds;
  char* Bs = lds + 16384;
  const int tid = threadIdx.x;
  const int lane = tid & 63;
  const int bn = blockIdx.x, bm = blockIdx.y;
  const int wm = tid >> 7, wn = (tid >> 6) & 1;

  f32x4 acc[4][4];
#pragma unroll
  for (int i = 0; i < 4; i++)
#pragma unroll
    for (int j = 0; j < 4; j++) acc[i][j] = (f32x4){0.f, 0.f, 0.f, 0.f};

  const size_t strideA = (size_t)K * 2;
  const char* ga[4];
  const char* gb[4];
#pragma unroll
  for (int t = 0; t < 4; t++) {
    int gg = t * 256 + tid;
    int row = gg >> 3, slot = gg & 7;
    ga[t] = (const char*)A + (size_t)(bm * 128 + row) * strideA + ((slot ^ (row & 7)) << 4);
    gb[t] = (const char*)BT + (size_t)(bn * 128 + row) * strideA + ((slot ^ (row & 7)) << 4);
  }

  for (int k0 = 0; k0 < K; k0 += 64) {
    __syncthreads();
#pragma unroll
    for (int t = 0; t < 4; t++) {
      int gg = t * 256 + tid;
      gload16(ga[t], As + gg * 16);
      gload16(gb[t], Bs + gg * 16);
      ga[t] += 128;
      gb[t] += 128;
    }
    __syncthreads();
#pragma unroll
    for (int kk = 0; kk < 2; kk++) {
      bf16x8 a[4], b[4];
      const int c16 = kk * 4 + (lane >> 4);
#pragma unroll
      for (int i = 0; i < 4; i++) {
        int ra = wm * 64 + i * 16 + (lane & 15);
        a[i] = *(const bf16x8*)(As + ra * 128 + ((c16 ^ (ra & 7)) << 4));
        int rb = wn * 64 + i * 16 + (lane & 15);
        b[i] = *(const bf16x8*)(Bs + rb * 128 + ((c16 ^ (rb & 7)) << 4));
      }
#pragma unroll
      for (int i = 0; i < 4; i++)
#pragma unroll
        for (int j = 0; j < 4; j++)
          acc[i][j] = __builtin_amdgcn_mfma_f32_16x16x32_bf16(a[i], b[j], acc[i][j], 0, 0, 0);
    }
  }

#pragma unroll
  for (int i = 0; i < 4; i++)
#pragma unroll
    for (int j = 0; j < 4; j++)
#pragma unroll
      for (int r = 0; r < 4; r++) {
        int row = bm * 128 + wm * 64 + i * 16 + ((lane >> 4) << 2) + r;
        int col = bn * 128 + wn * 64 + j * 16 + (lane & 15);
        size_t idx = (size_t)row * N + col;
        float v = acc[i][j][r];
        if (EPI == 0) {
          ((__bf16*)Cout)[idx] = (__bf16)v;
        } else if (EPI == 1) {
          ((float*)Cout)[idx] = v + res[idx];
        } else {
          float u = 0.7978845608028654f * (v + 0.044715f * v * v * v);
          ((__bf16*)Cout)[idx] = (__bf16)(0.5f * v * (1.0f + tanhf(u)));
        }
      }
}

// ---------------------------------------------------------------------------
// GEMM 256x256 8-phase (T2+T3+T4+T5) — used ONLY where grid == 256 blocks
// (fc: 16x16). Per-round rate ~1073 TF vs gemm_bt 895.
// ---------------------------------------------------------------------------
#define MMQ(IB, JB, AR, BR)                                                   \
  __builtin_amdgcn_s_setprio(1);                                              \
  _Pragma("unroll") for (int i = 0; i < 4; i++)                               \
      _Pragma("unroll") for (int j = 0; j < 2; j++)                           \
          _Pragma("unroll") for (int kk = 0; kk < 2; kk++)                    \
              acc[(IB)*4 + i][(JB)*2 + j] =                                   \
      __builtin_amdgcn_mfma_f32_16x16x32_bf16(                                \
          AR[i][kk], BR[j][kk], acc[(IB)*4 + i][(JB)*2 + j], 0, 0, 0);        \
  __builtin_amdgcn_s_setprio(0);

template <int EPI>
__global__ __launch_bounds__(512, 2) void gemm256(
    const __bf16* __restrict__ A, const __bf16* __restrict__ BT,
    void* __restrict__ Cout, const float* __restrict__ res, int M, int N, int K) {
  __shared__ char lds[131072];
  const int tid = threadIdx.x, lane = tid & 63, w = tid >> 6;
  const int wm = w >> 2, wn = w & 3;
  const int bn = blockIdx.x, bm = blockIdx.y;

  f32x4 acc[8][4];
#pragma unroll
  for (int i = 0; i < 8; i++)
#pragma unroll
    for (int j = 0; j < 4; j++) acc[i][j] = (f32x4){0.f, 0.f, 0.f, 0.f};

  const size_t strideA = (size_t)K * 2;
  const int r0 = tid >> 3, s0 = tid & 7;
  const int r1 = r0 + 64;
  const char* Ab0 = (const char*)A + (size_t)(bm * 256) * strideA;
  const char* Bb0 = (const char*)BT + (size_t)(bn * 256) * strideA;

  auto stage = [&](int isB, int h, int kt, int buf) {
    const char* g = (isB ? Bb0 : Ab0) + (size_t)(h * 128) * strideA + (size_t)kt * 128;
    char* d = lds + isB * 65536 + buf * 32768 + h * 16384;
    gload16(g + (size_t)r0 * strideA + ((s0 ^ (r0 & 7)) << 4), d + tid * 16);
    gload16(g + (size_t)r1 * strideA + ((s0 ^ (r1 & 7)) << 4), d + (tid + 512) * 16);
  };
  auto ldA = [&](bf16x8 (&a)[4][2], int buf, int bank) {
    const char* base = lds + buf * 32768 + wm * 16384;
#pragma unroll
    for (int i = 0; i < 4; i++)
#pragma unroll
      for (int kk = 0; kk < 2; kk++) {
        int rl = bank * 64 + i * 16 + (lane & 15);
        int c16 = kk * 4 + (lane >> 4);
        a[i][kk] = *(const bf16x8*)(base + rl * 128 + ((c16 ^ (rl & 7)) << 4));
      }
  };
  auto ldB = [&](bf16x8 (&b)[2][2], int buf, int jb) {
    const char* base = lds + 65536 + buf * 32768 + (wn >> 1) * 16384;
#pragma unroll
    for (int j = 0; j < 2; j++)
#pragma unroll
      for (int kk = 0; kk < 2; kk++) {
        int rl = (wn & 1) * 64 + jb * 32 + j * 16 + (lane & 15);
        int c16 = kk * 4 + (lane >> 4);
        b[j][kk] = *(const bf16x8*)(base + rl * 128 + ((c16 ^ (rl & 7)) << 4));
      }
  };

  const int NT = K >> 6;
  stage(1, 0, 0, 0); stage(1, 1, 0, 0); stage(0, 0, 0, 0); stage(0, 1, 0, 0);
  stage(1, 0, 1, 1); stage(1, 1, 1, 1); stage(0, 0, 1, 1); stage(0, 1, 1, 1);
  asm volatile("s_waitcnt vmcnt(6)" ::: "memory");
  __builtin_amdgcn_s_barrier();

  bf16x8 a[4][2], b0[2][2], b1[2][2];
  for (int it = 0; it < (NT >> 1); ++it) {
    const int e = 2 * it;
    const int ep = (e + 2 < NT) ? e + 2 : NT - 1;
    const int op = (e + 3 < NT) ? e + 3 : NT - 1;
    ldA(a, 0, 0); ldB(b0, 0, 0);
    __builtin_amdgcn_s_barrier();
    MMQ(0, 0, a, b0);
    __builtin_amdgcn_s_barrier();
    ldB(b1, 0, 1);
    __builtin_amdgcn_s_barrier();
    MMQ(0, 1, a, b1);
    __builtin_amdgcn_s_barrier();
    ldA(a, 0, 1); stage(1, 0, ep, 0);
    __builtin_amdgcn_s_barrier();
    MMQ(1, 1, a, b1);
    __builtin_amdgcn_s_barrier();
    stage(1, 1, ep, 0);
    asm volatile("s_waitcnt vmcnt(4)" ::: "memory");
    __builtin_amdgcn_s_barrier();
    MMQ(1, 0, a, b0);
    __builtin_amdgcn_s_barrier();
    ldA(a, 1, 0); ldB(b0, 1, 0); stage(0, 0, ep, 0);
    __builtin_amdgcn_s_barrier();
    MMQ(0, 0, a, b0);
    __builtin_amdgcn_s_barrier();
    ldB(b1, 1, 1); stage(0, 1, ep, 0);
    __builtin_amdgcn_s_barrier();
    MMQ(0, 1, a, b1);
    __builtin_amdgcn_s_barrier();
    ldA(a, 1, 1); stage(1, 0, op, 1);
    __builtin_amdgcn_s_barrier();
    MMQ(1, 1, a, b1);
    __builtin_amdgcn_s_barrier();
    stage(1, 1, op, 1); stage(0, 0, op, 1); stage(0, 1, op, 1);
    asm volatile("s_waitcnt vmcnt(6)" ::: "memory");
    __builtin_amdgcn_s_barrier();
    MMQ(1, 0, a, b0);
    __builtin_amdgcn_s_barrier();
  }
  asm volatile("s_waitcnt vmcnt(0)" ::: "memory");

#pragma unroll
  for (int i = 0; i < 8; i++)
#pragma unroll
    for (int j = 0; j < 4; j++)
#pragma unroll
      for (int r = 0; r < 4; r++) {
        int row = bm * 256 + wm * 128 + i * 16 + ((lane >> 4) << 2) + r;
        int col = bn * 256 + wn * 64 + j * 16 + (lane & 15);
        size_t idx = (size_t)row * N + col;
        float v = acc[i][j][r];
        if (EPI == 0) {
          ((__bf16*)Cout)[idx] = (__bf16)v;
        } else if (EPI == 1) {
          ((float*)Cout)[idx] = v + res[idx];
        } else {
          float u = 0.7978845608028654f * (v + 0.044715f * v * v * v);
          ((__bf16*)Cout)[idx] = (__bf16)(0.5f * v * (1.0f + tanhf(u)));
        }
      }
}

// ---------------------------------------------------------------------------
// RoPE tables: cos/sin [2048][64] f32 (cos at [0], sin at +131072 elems).
// ---------------------------------------------------------------------------
__global__ __launch_bounds__(256) void rope_tables(float* __restrict__ tab) {
  const int idx = blockIdx.x * 256 + threadIdx.x;  // 131072
  const int s = idx >> 6, j = idx & 63;
  const float inv = powf(10000.0f, -(float)j / 64.0f);
  const float a = (float)s * inv;
  tab[idx] = cosf(a);
  tab[131072 + idx] = sinf(a);
}

// ---------------------------------------------------------------------------
// RoPE apply + head split, vectorized: one thread = 8 bf16 (4 pairs) of q AND
// k. bf16x8 loads/stores, float4 table reads. 1M threads.
// ---------------------------------------------------------------------------
__global__ __launch_bounds__(256) void rope_apply(
    const __bf16* __restrict__ qkv, const float* __restrict__ tab,
    __bf16* __restrict__ qr, __bf16* __restrict__ kr) {
  const int idx = blockIdx.x * 256 + threadIdx.x;  // 1048576
  const int ch = idx & 15;           // 8-elem chunk within head dim
  const int h = (idx >> 4) & 15;
  const int s = (idx >> 8) & 2047;
  const int b = idx >> 19;
  const float4 c4 = *(const float4*)(tab + (s << 6) + ch * 4);
  const float4 s4 = *(const float4*)(tab + 131072 + (s << 6) + ch * 4);
  const float cc[4] = {c4.x, c4.y, c4.z, c4.w};
  const float ss[4] = {s4.x, s4.y, s4.z, s4.w};
  const size_t qi = ((size_t)(b * 2048 + s)) * 6144 + h * 128 + ch * 8;
  const size_t qo = ((size_t)((b * 16 + h) * 2048 + s)) * 128 + ch * 8;
  bf16x8 vq = *(const bf16x8*)(qkv + qi);
  bf16x8 vk = *(const bf16x8*)(qkv + qi + 2048);
  bf16x8 oq, ok;
#pragma unroll
  for (int p = 0; p < 4; p++) {
    float e = (float)vq[2 * p], o = (float)vq[2 * p + 1];
    oq[2 * p] = (__bf16)(e * cc[p] - o * ss[p]);
    oq[2 * p + 1] = (__bf16)(o * cc[p] + e * ss[p]);
    e = (float)vk[2 * p]; o = (float)vk[2 * p + 1];
    ok[2 * p] = (__bf16)(e * cc[p] - o * ss[p]);
    ok[2 * p + 1] = (__bf16)(o * cc[p] + e * ss[p]);
  }
  *(bf16x8*)(qr + qo) = oq;
  *(bf16x8*)(kr + qo) = ok;
}

// ---------------------------------------------------------------------------
// V transpose: qkv v-part [B*S][6144] -> vt bf16 [B][H][128][S].
// ---------------------------------------------------------------------------
__global__ __launch_bounds__(256) void v_transpose(
    const __bf16* __restrict__ qkv, __bf16* __restrict__ vt) {
  __shared__ __bf16 t[32][33];
  const int s0 = blockIdx.x * 32, d0 = blockIdx.y * 32, bh = blockIdx.z;
  const int b = bh >> 4, h = bh & 15;
  const int tx = threadIdx.x, ty = threadIdx.y;  // (32,8)
#pragma unroll
  for (int i = 0; i < 4; i++)
    t[ty + 8 * i][tx] =
        qkv[((size_t)(b * 2048 + s0 + ty + 8 * i)) * 6144 + 4096 + h * 128 + d0 + tx];
  __syncthreads();
#pragma unroll
  for (int i = 0; i < 4; i++)
    vt[((size_t)bh * 128 + d0 + ty + 8 * i) * 2048 + s0 + tx] = t[tx][ty + 8 * i];
}

// ---------------------------------------------------------------------------
// Flash attention v2 (causal). QBLK=128 (8 waves x 16 q-rows), KVBLK=64.
// (unchanged — verified)
// ---------------------------------------------------------------------------
__global__ __launch_bounds__(512) void flash_attn(
    const __bf16* __restrict__ qg, const __bf16* __restrict__ kg,
    const __bf16* __restrict__ vtg, __bf16* __restrict__ og) {
  __shared__ char lds[81920];
  const int tid = threadIdx.x, lane = tid & 63, w = tid >> 6;  // w 0..7
  const int h = blockIdx.y, b = blockIdx.z;
  const int bh = b * 16 + h;
  const __bf16* qb = qg + (size_t)bh * 2048 * 128;
  const char* kbb = (const char*)(kg + (size_t)bh * 2048 * 128);
  const char* vbb = (const char*)(vtg + (size_t)bh * 128 * 2048);
  char* Pw = lds + 65536 + w * 2048;

  const char* gK[2];
  const char* gV[2];
#pragma unroll
  for (int t = 0; t < 2; t++) {
    int gg = t * 512 + tid;           // 0..1023
    int rk = gg >> 4, sk = gg & 15;   // K row 0..63, slot 0..15
    gK[t] = kbb + rk * 256 + ((sk ^ (rk & 15)) << 4);
    int rv = gg >> 3, sv = gg & 7;    // V row 0..127, slot 0..7
    gV[t] = vbb + rv * 4096 + ((sv ^ (rv & 7)) << 4);
  }

  const float SL2E = 0.08838834764831845f * 1.4426950408889634f;  // scale*log2(e)

  auto stageKV = [&](int kt, int buf) {
#pragma unroll
    for (int t = 0; t < 2; t++) {
      int gg = t * 512 + tid;
      gload16(gK[t] + (size_t)kt * 16384, lds + buf * 16384 + gg * 16);
      gload16(gV[t] + (size_t)kt * 128, lds + 32768 + buf * 16384 + gg * 16);
    }
  };

  auto run_qtile = [&](int qt) {
    const int qrow0 = qt * 128 + w * 16;
    bf16x8 qf[4];
#pragma unroll
    for (int c = 0; c < 4; c++) {
      bf16x8 raw = *(const bf16x8*)(qb + (size_t)(qrow0 + (lane & 15)) * 128 +
                                    c * 32 + ((lane >> 4) << 3));
#pragma unroll
      for (int e = 0; e < 8; e++) qf[c][e] = (__bf16)((float)raw[e] * SL2E);
    }
    float m[4], lsp[4];
    f32x4 o[8];
#pragma unroll
    for (int r = 0; r < 4; r++) { m[r] = -__builtin_inff(); lsp[r] = 0.f; }
#pragma unroll
    for (int n = 0; n < 8; n++) o[n] = (f32x4){0.f, 0.f, 0.f, 0.f};

    const int NKT = 2 * qt + 2;
    stageKV(0, 0);

    for (int kt = 0; kt < NKT; kt++) {
      const int cur = kt & 1;
      const char* Ks = lds + cur * 16384;
      const char* Vs = lds + 32768 + cur * 16384;
      if (kt < NKT - 1) {
        stageKV(kt + 1, cur ^ 1);
        asm volatile("s_waitcnt vmcnt(4)" ::: "memory");  // current tile landed
      } else {
        asm volatile("s_waitcnt vmcnt(0)" ::: "memory");
      }
      __builtin_amdgcn_s_barrier();

      f32x4 s[4];
      __builtin_amdgcn_s_setprio(1);
#pragma unroll
      for (int n = 0; n < 4; n++) {
        s[n] = (f32x4){0.f, 0.f, 0.f, 0.f};
#pragma unroll
        for (int c = 0; c < 4; c++) {
          int krow = n * 16 + (lane & 15);
          int c16 = c * 4 + (lane >> 4);
          bf16x8 kf = *(const bf16x8*)(Ks + krow * 256 + ((c16 ^ (krow & 15)) << 4));
          s[n] = __builtin_amdgcn_mfma_f32_16x16x32_bf16(qf[c], kf, s[n], 0, 0, 0);
        }
      }
      __builtin_amdgcn_s_setprio(0);

      if (kt * 64 + 63 > qrow0) {
#pragma unroll
        for (int r = 0; r < 4; r++) {
          const int qrow = qrow0 + ((lane >> 4) << 2) + r;
#pragma unroll
          for (int n = 0; n < 4; n++) {
            int col = kt * 64 + n * 16 + (lane & 15);
            if (col > qrow) s[n][r] = -__builtin_inff();
          }
        }
      }

      float tmx[4];
#pragma unroll
      for (int r = 0; r < 4; r++)
        tmx[r] = fmaxf(fmaxf(s[0][r], s[1][r]), fmaxf(s[2][r], s[3][r]));
      bool hot = (tmx[0] > m[0] + 8.f) | (tmx[1] > m[1] + 8.f) |
                 (tmx[2] > m[2] + 8.f) | (tmx[3] > m[3] + 8.f);
      if (__any(hot)) {
        float fc[4];
#pragma unroll
        for (int r = 0; r < 4; r++) {
          float gmx = tmx[r];
#pragma unroll
          for (int mk = 1; mk < 16; mk <<= 1) gmx = fmaxf(gmx, __shfl_xor(gmx, mk));
          float nm = fmaxf(m[r], gmx);
          fc[r] = __builtin_amdgcn_exp2f(m[r] - nm);
          m[r] = nm;
          lsp[r] *= fc[r];
        }
#pragma unroll
        for (int n = 0; n < 8; n++) {
          o[n][0] *= fc[0]; o[n][1] *= fc[1]; o[n][2] *= fc[2]; o[n][3] *= fc[3];
        }
      }

      float p[4][4];
#pragma unroll
      for (int r = 0; r < 4; r++) {
        float sum = 0.f;
#pragma unroll
        for (int n = 0; n < 4; n++) {
          float pv = __builtin_amdgcn_exp2f(s[n][r] - m[r]);
          p[n][r] = pv;
          sum += pv;
        }
        lsp[r] += sum;
      }

#pragma unroll
      for (int n = 0; n < 4; n++)
#pragma unroll
        for (int r = 0; r < 4; r++) {
          int prow = ((lane >> 4) << 2) + r;
          int col = n * 16 + (lane & 15);
          int ch = col >> 3;
          *(__bf16*)(Pw + prow * 128 + ((ch ^ (prow & 7)) << 4) + ((col & 7) << 1)) =
              (__bf16)p[n][r];
        }

      __builtin_amdgcn_s_setprio(1);
#pragma unroll
      for (int kk = 0; kk < 2; kk++) {
        int prow = lane & 15;
        int pc = kk * 4 + (lane >> 4);
        bf16x8 pf = *(const bf16x8*)(Pw + prow * 128 + ((pc ^ (prow & 7)) << 4));
#pragma unroll
        for (int n = 0; n < 8; n++) {
          int vr = n * 16 + (lane & 15);
          bf16x8 vf = *(const bf16x8*)(Vs + vr * 128 + ((pc ^ (vr & 7)) << 4));
          o[n] = __builtin_amdgcn_mfma_f32_16x16x32_bf16(pf, vf, o[n], 0, 0, 0);
        }
      }
      __builtin_amdgcn_s_setprio(0);
      __builtin_amdgcn_s_barrier();
    }

    float inv[4];
#pragma unroll
    for (int r = 0; r < 4; r++) {
      float ls = lsp[r];
#pragma unroll
      for (int mk = 1; mk < 16; mk <<= 1) ls += __shfl_xor(ls, mk);
      inv[r] = 1.0f / ls;
    }
#pragma unroll
    for (int n = 0; n < 8; n++)
#pragma unroll
      for (int r = 0; r < 4; r++) {
        int qrow = qrow0 + ((lane >> 4) << 2) + r;
        og[(size_t)(b * 2048 + qrow) * 2048 + h * 128 + n * 16 + (lane & 15)] =
            (__bf16)(o[n][r] * inv[r]);
      }
  };

  run_qtile(15 - (int)blockIdx.x);
  run_qtile((int)blockIdx.x);
}

// ---------------------------------------------------------------------------
extern "C" void kernel_launch(void* const* d_in, const int* in_sizes, int n_in,
                              void* d_out, int out_size, void* d_ws, size_t ws_size,
                              hipStream_t stream) {
  const float* x = (const float*)d_in[0];
  const float* w_qkv = (const float*)d_in[1];
  const float* w_out = (const float*)d_in[2];
  const float* w_fc = (const float*)d_in[3];
  const float* w_proj = (const float*)d_in[4];
  const float* g_in = (const float*)d_in[5];
  const float* g_ff = (const float*)d_in[6];
  float* out = (float*)d_out;
  char* ws = (char*)d_ws;

  constexpr size_t O_WQKV = 0;           // bf16 [6144][2048]
  constexpr size_t O_WOUT = 25165824;    // bf16 [2048][2048]
  constexpr size_t O_WFC = 33554432;     // bf16 [4096][2048]
  constexpr size_t O_WPROJ = 50331648;   // bf16 [2048][4096]
  constexpr size_t O_H = 67108864;       // bf16 [4096][2048]
  constexpr size_t O_QKV = 83886080;     // bf16 [4096][6144] (later fcact [4096][4096])
  constexpr size_t O_Q = 134217728;      // bf16 [2][16][2048][128]
  constexpr size_t O_K = 150994944;
  constexpr size_t O_VT = 167772160;     // bf16 [2][16][128][2048]
  constexpr size_t O_TAB = 184549376;    // f32 cos/sin [2][2048][64]
  constexpr size_t O_ATTN = 185597952;   // bf16 [4096][2048]
  constexpr size_t O_X1 = 202375168;     // f32 [4096][2048]

  __bf16* wqkvT = (__bf16*)(ws + O_WQKV);
  __bf16* woutT = (__bf16*)(ws + O_WOUT);
  __bf16* wfcT = (__bf16*)(ws + O_WFC);
  __bf16* wprojT = (__bf16*)(ws + O_WPROJ);
  __bf16* h = (__bf16*)(ws + O_H);
  __bf16* qkv = (__bf16*)(ws + O_QKV);
  __bf16* fcact = (__bf16*)(ws + O_QKV);
  __bf16* qr = (__bf16*)(ws + O_Q);
  __bf16* kr = (__bf16*)(ws + O_K);
  __bf16* vt = (__bf16*)(ws + O_VT);
  float* tab = (float*)(ws + O_TAB);
  __bf16* attn = (__bf16*)(ws + O_ATTN);
  float* x1 = (float*)(ws + O_X1);

  // weight convert+transpose (64x64 tiles)
  transpose_cvt<<<dim3(96, 32), 256, 0, stream>>>(w_qkv, wqkvT, 2048, 6144);
  transpose_cvt<<<dim3(32, 32), 256, 0, stream>>>(w_out, woutT, 2048, 2048);
  transpose_cvt<<<dim3(64, 32), 256, 0, stream>>>(w_fc, wfcT, 2048, 4096);
  transpose_cvt<<<dim3(32, 64), 256, 0, stream>>>(w_proj, wprojT, 4096, 2048);

  // h = rmsnorm(x, g_in)
  rmsnorm_kernel<<<4096, 256, 0, stream>>>(x, g_in, h);
  // qkv = h @ w_qkv  (128^2, grid 48x32 = 6 exact rounds)
  gemm_bt<0><<<dim3(48, 32), 256, 0, stream>>>(h, wqkvT, (void*)qkv, nullptr, 4096, 6144, 2048);
  // rope
  rope_tables<<<512, 256, 0, stream>>>(tab);
  rope_apply<<<4096, 256, 0, stream>>>(qkv, tab, qr, kr);
  v_transpose<<<dim3(64, 4, 32), dim3(32, 8), 0, stream>>>(qkv, vt);
  // attention (QBLK=128, balanced pairs)
  flash_attn<<<dim3(8, 16, 2), 512, 0, stream>>>(qr, kr, vt, attn);
  // x1 = x + attn @ w_out
  gemm_bt<1><<<dim3(16, 32), 256, 0, stream>>>(attn, woutT, (void*)x1, x, 4096, 2048, 2048);
  // h2 = rmsnorm(x1, g_ff)
  rmsnorm_kernel<<<4096, 256, 0, stream>>>(x1, g_ff, h);
  // fcact = gelu(h2 @ w_fc)  (256^2 8-phase, grid 16x16 = exactly 1 round)
  gemm256<2><<<dim3(16, 16), 512, 0, stream>>>(h, wfcT, (void*)fcact, nullptr, 4096, 4096, 2048);
  // out = x1 + fcact @ w_proj
  gemm_bt<1><<<dim3(16, 32), 256, 0, stream>>>(fcact, wprojT, (void*)out, x1, 4096, 2048, 4096);
}

// Round 8
// 459.860 us; speedup vs baseline: 1.2181x; 1.0626x over previous
//
#include <hip/hip_runtime.h>
#include <math.h>

typedef __bf16 bf16x8 __attribute__((ext_vector_type(8)));
typedef __bf16 bf16x4 __attribute__((ext_vector_type(4)));
typedef float  f32x4  __attribute__((ext_vector_type(4)));

#define DEV __device__ __forceinline__

DEV void gload16(const void* g, void* l) {
  __builtin_amdgcn_global_load_lds(
      (const __attribute__((address_space(1))) void*)g,
      (__attribute__((address_space(3))) void*)l, 16, 0, 0);
}

// ---------------------------------------------------------------------------
// Weight f32 [R][C] -> bf16 [C][R], 64x64 tiles, float4 reads / bf16x8 writes.
// ---------------------------------------------------------------------------
__global__ __launch_bounds__(256) void transpose_cvt(
    const float* __restrict__ in, __bf16* __restrict__ outT, int R, int C) {
  __shared__ float t[64][65];
  const int c0 = blockIdx.x * 64, r0 = blockIdx.y * 64;
  const int tid = threadIdx.x;
#pragma unroll
  for (int i = 0; i < 4; i++) {
    int r = (tid >> 4) + i * 16;
    int cf = tid & 15;
    float4 v = *(const float4*)(in + (size_t)(r0 + r) * C + c0 + cf * 4);
    t[r][cf * 4 + 0] = v.x; t[r][cf * 4 + 1] = v.y;
    t[r][cf * 4 + 2] = v.z; t[r][cf * 4 + 3] = v.w;
  }
  __syncthreads();
#pragma unroll
  for (int i = 0; i < 2; i++) {
    int c = (tid >> 3) + i * 32;
    int r8 = tid & 7;
    bf16x8 ov;
#pragma unroll
    for (int k = 0; k < 8; k++) ov[k] = (__bf16)t[r8 * 8 + k][c];
    *(bf16x8*)(outT + (size_t)(c0 + c) * R + r0 + r8 * 8) = ov;
  }
}

// ---------------------------------------------------------------------------
// RMSNorm row kernel: f32 [rows][2048] -> bf16, 1 block/row, 8 elems/thread.
// ---------------------------------------------------------------------------
__global__ __launch_bounds__(256) void rmsnorm_kernel(
    const float* __restrict__ x, const float* __restrict__ g, __bf16* __restrict__ out) {
  const int r = blockIdx.x, t = threadIdx.x;
  const float4* xr = (const float4*)(x + (size_t)r * 2048);
  float4 a = xr[2 * t], b = xr[2 * t + 1];
  float ss = a.x * a.x + a.y * a.y + a.z * a.z + a.w * a.w +
             b.x * b.x + b.y * b.y + b.z * b.z + b.w * b.w;
#pragma unroll
  for (int mk = 1; mk < 64; mk <<= 1) ss += __shfl_xor(ss, mk);
  __shared__ float red[4];
  if ((t & 63) == 0) red[t >> 6] = ss;
  __syncthreads();
  const float sc = rsqrtf((red[0] + red[1] + red[2] + red[3]) * (1.0f / 2048.0f) + 1e-6f);
  const float4* gr = (const float4*)g;
  float4 ga = gr[2 * t], gb = gr[2 * t + 1];
  bf16x8 ov;
  ov[0] = (__bf16)(a.x * sc * ga.x); ov[1] = (__bf16)(a.y * sc * ga.y);
  ov[2] = (__bf16)(a.z * sc * ga.z); ov[3] = (__bf16)(a.w * sc * ga.w);
  ov[4] = (__bf16)(b.x * sc * gb.x); ov[5] = (__bf16)(b.y * sc * gb.y);
  ov[6] = (__bf16)(b.z * sc * gb.z); ov[7] = (__bf16)(b.w * sc * gb.w);
  *(bf16x8*)(out + (size_t)r * 2048 + t * 8) = ov;
}

// ---------------------------------------------------------------------------
// GEMM 128x128 (m97 structure, 895 TF) — wout / proj.
// EPI: 0 = bf16 store, 1 = f32 store + residual, 2 = gelu -> bf16.
// ---------------------------------------------------------------------------
template <int EPI>
__global__ __launch_bounds__(256) void gemm_bt(
    const __bf16* __restrict__ A, const __bf16* __restrict__ BT,
    void* __restrict__ Cout, const float* __restrict__ res, int M, int N, int K) {
  __shared__ char lds[32768];
  char* As = lds;
  char* Bs = lds + 16384;
  const int tid = threadIdx.x;
  const int lane = tid & 63;
  const int bn = blockIdx.x, bm = blockIdx.y;
  const int wm = tid >> 7, wn = (tid >> 6) & 1;

  f32x4 acc[4][4];
#pragma unroll
  for (int i = 0; i < 4; i++)
#pragma unroll
    for (int j = 0; j < 4; j++) acc[i][j] = (f32x4){0.f, 0.f, 0.f, 0.f};

  const size_t strideA = (size_t)K * 2;
  const char* ga[4];
  const char* gb[4];
#pragma unroll
  for (int t = 0; t < 4; t++) {
    int gg = t * 256 + tid;
    int row = gg >> 3, slot = gg & 7;
    ga[t] = (const char*)A + (size_t)(bm * 128 + row) * strideA + ((slot ^ (row & 7)) << 4);
    gb[t] = (const char*)BT + (size_t)(bn * 128 + row) * strideA + ((slot ^ (row & 7)) << 4);
  }

  for (int k0 = 0; k0 < K; k0 += 64) {
    __syncthreads();
#pragma unroll
    for (int t = 0; t < 4; t++) {
      int gg = t * 256 + tid;
      gload16(ga[t], As + gg * 16);
      gload16(gb[t], Bs + gg * 16);
      ga[t] += 128;
      gb[t] += 128;
    }
    __syncthreads();
#pragma unroll
    for (int kk = 0; kk < 2; kk++) {
      bf16x8 a[4], b[4];
      const int c16 = kk * 4 + (lane >> 4);
#pragma unroll
      for (int i = 0; i < 4; i++) {
        int ra = wm * 64 + i * 16 + (lane & 15);
        a[i] = *(const bf16x8*)(As + ra * 128 + ((c16 ^ (ra & 7)) << 4));
        int rb = wn * 64 + i * 16 + (lane & 15);
        b[i] = *(const bf16x8*)(Bs + rb * 128 + ((c16 ^ (rb & 7)) << 4));
      }
#pragma unroll
      for (int i = 0; i < 4; i++)
#pragma unroll
        for (int j = 0; j < 4; j++)
          acc[i][j] = __builtin_amdgcn_mfma_f32_16x16x32_bf16(a[i], b[j], acc[i][j], 0, 0, 0);
    }
  }

#pragma unroll
  for (int i = 0; i < 4; i++)
#pragma unroll
    for (int j = 0; j < 4; j++)
#pragma unroll
      for (int r = 0; r < 4; r++) {
        int row = bm * 128 + wm * 64 + i * 16 + ((lane >> 4) << 2) + r;
        int col = bn * 128 + wn * 64 + j * 16 + (lane & 15);
        size_t idx = (size_t)row * N + col;
        float v = acc[i][j][r];
        if (EPI == 0) {
          ((__bf16*)Cout)[idx] = (__bf16)v;
        } else if (EPI == 1) {
          ((float*)Cout)[idx] = v + res[idx];
        } else {
          float u = 0.7978845608028654f * (v + 0.044715f * v * v * v);
          ((__bf16*)Cout)[idx] = (__bf16)(0.5f * v * (1.0f + tanhf(u)));
        }
      }
}

// ---------------------------------------------------------------------------
// QKV GEMM with fused RoPE + head-split + V-transpose epilogue.
// cols 0..4095 (q/k): rope pair = adjacent lanes -> __shfl_xor(acc,1);
// cols 4096..6143 (v): transposed store to vt via bf16x4.
// ---------------------------------------------------------------------------
__global__ __launch_bounds__(256) void gemm_qkv(
    const __bf16* __restrict__ A, const __bf16* __restrict__ BT,
    const float2* __restrict__ tab, __bf16* __restrict__ qr,
    __bf16* __restrict__ kr, __bf16* __restrict__ vt, int K) {
  __shared__ char lds[32768];
  char* As = lds;
  char* Bs = lds + 16384;
  const int tid = threadIdx.x;
  const int lane = tid & 63;
  const int bn = blockIdx.x, bm = blockIdx.y;
  const int wm = tid >> 7, wn = (tid >> 6) & 1;

  f32x4 acc[4][4];
#pragma unroll
  for (int i = 0; i < 4; i++)
#pragma unroll
    for (int j = 0; j < 4; j++) acc[i][j] = (f32x4){0.f, 0.f, 0.f, 0.f};

  const size_t strideA = (size_t)K * 2;
  const char* ga[4];
  const char* gb[4];
#pragma unroll
  for (int t = 0; t < 4; t++) {
    int gg = t * 256 + tid;
    int row = gg >> 3, slot = gg & 7;
    ga[t] = (const char*)A + (size_t)(bm * 128 + row) * strideA + ((slot ^ (row & 7)) << 4);
    gb[t] = (const char*)BT + (size_t)(bn * 128 + row) * strideA + ((slot ^ (row & 7)) << 4);
  }

  for (int k0 = 0; k0 < K; k0 += 64) {
    __syncthreads();
#pragma unroll
    for (int t = 0; t < 4; t++) {
      int gg = t * 256 + tid;
      gload16(ga[t], As + gg * 16);
      gload16(gb[t], Bs + gg * 16);
      ga[t] += 128;
      gb[t] += 128;
    }
    __syncthreads();
#pragma unroll
    for (int kk = 0; kk < 2; kk++) {
      bf16x8 a[4], b[4];
      const int c16 = kk * 4 + (lane >> 4);
#pragma unroll
      for (int i = 0; i < 4; i++) {
        int ra = wm * 64 + i * 16 + (lane & 15);
        a[i] = *(const bf16x8*)(As + ra * 128 + ((c16 ^ (ra & 7)) << 4));
        int rb = wn * 64 + i * 16 + (lane & 15);
        b[i] = *(const bf16x8*)(Bs + rb * 128 + ((c16 ^ (rb & 7)) << 4));
      }
#pragma unroll
      for (int i = 0; i < 4; i++)
#pragma unroll
        for (int j = 0; j < 4; j++)
          acc[i][j] = __builtin_amdgcn_mfma_f32_16x16x32_bf16(a[i], b[j], acc[i][j], 0, 0, 0);
    }
  }

  const int colbase = bn * 128 + wn * 64;
  if (bn < 32) {
    // q/k region with RoPE
#pragma unroll
    for (int i = 0; i < 4; i++)
#pragma unroll
      for (int j = 0; j < 4; j++) {
        int col = colbase + j * 16 + (lane & 15);
        int isK = col >> 11;                 // 0:q 1:k (block never straddles)
        int hh = (col >> 7) & 15, d = col & 127, jj = d >> 1;
        __bf16* dst = isK ? kr : qr;
#pragma unroll
        for (int r = 0; r < 4; r++) {
          int row = bm * 128 + wm * 64 + i * 16 + ((lane >> 4) << 2) + r;
          int bb = row >> 11, srel = row & 2047;
          float2 cs = tab[(srel << 6) + jj];
          float me = acc[i][j][r];
          float pv = __shfl_xor(me, 1);
          float ov = (lane & 1) ? (me * cs.x + pv * cs.y)
                                : (me * cs.x - pv * cs.y);
          dst[((size_t)((bb * 16 + hh) * 2048 + srel)) * 128 + d] = (__bf16)ov;
        }
      }
  } else {
    // v region -> transposed store
#pragma unroll
    for (int i = 0; i < 4; i++)
#pragma unroll
      for (int j = 0; j < 4; j++) {
        int col = colbase + j * 16 + (lane & 15) - 4096;
        int hh = col >> 7, d = col & 127;
        int row0 = bm * 128 + wm * 64 + i * 16 + ((lane >> 4) << 2);
        int bb = row0 >> 11, srel = row0 & 2047;
        bf16x4 pk;
#pragma unroll
        for (int r = 0; r < 4; r++) pk[r] = (__bf16)acc[i][j][r];
        *(bf16x4*)(vt + ((size_t)((bb * 16 + hh) * 128 + d)) * 2048 + srel) = pk;
      }
  }
}

// ---------------------------------------------------------------------------
// GEMM 256x256 8-phase — REVERTED to the R4/R5 proven schedule.
// Stage slots: ph3:B0(T+2) ph4:B1(T+2)+vmcnt(4) ph5:A0(T+2) ph6:A1(T+2)
// ph7:B0(T+3) ph8:B1+A0+A1(T+3)+vmcnt(6). A-half h is read at ph1&ph3 (even
// tile) / ph5&ph7 (odd), so A stages must come no earlier than ph5/ph8 resp.
// ---------------------------------------------------------------------------
#define MMQ(IB, JB, AR, BR)                                                   \
  __builtin_amdgcn_s_setprio(1);                                              \
  _Pragma("unroll") for (int i = 0; i < 4; i++)                               \
      _Pragma("unroll") for (int j = 0; j < 2; j++)                           \
          _Pragma("unroll") for (int kk = 0; kk < 2; kk++)                    \
              acc[(IB)*4 + i][(JB)*2 + j] =                                   \
      __builtin_amdgcn_mfma_f32_16x16x32_bf16(                                \
          AR[i][kk], BR[j][kk], acc[(IB)*4 + i][(JB)*2 + j], 0, 0, 0);        \
  __builtin_amdgcn_s_setprio(0);

template <int EPI>
__global__ __launch_bounds__(512, 2) void gemm256(
    const __bf16* __restrict__ A, const __bf16* __restrict__ BT,
    void* __restrict__ Cout, const float* __restrict__ res, int M, int N, int K) {
  __shared__ char lds[131072];
  const int tid = threadIdx.x, lane = tid & 63, w = tid >> 6;
  const int wm = w >> 2, wn = w & 3;
  const int bn = blockIdx.x, bm = blockIdx.y;

  f32x4 acc[8][4];
#pragma unroll
  for (int i = 0; i < 8; i++)
#pragma unroll
    for (int j = 0; j < 4; j++) acc[i][j] = (f32x4){0.f, 0.f, 0.f, 0.f};

  const size_t strideA = (size_t)K * 2;
  const int r0 = tid >> 3, s0 = tid & 7;
  const int r1 = r0 + 64;
  const char* Ab0 = (const char*)A + (size_t)(bm * 256) * strideA;
  const char* Bb0 = (const char*)BT + (size_t)(bn * 256) * strideA;

  auto stage = [&](int isB, int h, int kt, int buf) {
    const char* g = (isB ? Bb0 : Ab0) + (size_t)(h * 128) * strideA + (size_t)kt * 128;
    char* d = lds + isB * 65536 + buf * 32768 + h * 16384;
    gload16(g + (size_t)r0 * strideA + ((s0 ^ (r0 & 7)) << 4), d + tid * 16);
    gload16(g + (size_t)r1 * strideA + ((s0 ^ (r1 & 7)) << 4), d + (tid + 512) * 16);
  };
  auto ldA = [&](bf16x8 (&a)[4][2], int buf, int bank) {
    const char* base = lds + buf * 32768 + wm * 16384;
#pragma unroll
    for (int i = 0; i < 4; i++)
#pragma unroll
      for (int kk = 0; kk < 2; kk++) {
        int rl = bank * 64 + i * 16 + (lane & 15);
        int c16 = kk * 4 + (lane >> 4);
        a[i][kk] = *(const bf16x8*)(base + rl * 128 + ((c16 ^ (rl & 7)) << 4));
      }
  };
  auto ldB = [&](bf16x8 (&b)[2][2], int buf, int jb) {
    const char* base = lds + 65536 + buf * 32768 + (wn >> 1) * 16384;
#pragma unroll
    for (int j = 0; j < 2; j++)
#pragma unroll
      for (int kk = 0; kk < 2; kk++) {
        int rl = (wn & 1) * 64 + jb * 32 + j * 16 + (lane & 15);
        int c16 = kk * 4 + (lane >> 4);
        b[j][kk] = *(const bf16x8*)(base + rl * 128 + ((c16 ^ (rl & 7)) << 4));
      }
  };

  const int NT = K >> 6;
  stage(1, 0, 0, 0); stage(1, 1, 0, 0); stage(0, 0, 0, 0); stage(0, 1, 0, 0);
  stage(1, 0, 1, 1); stage(1, 1, 1, 1); stage(0, 0, 1, 1); stage(0, 1, 1, 1);
  asm volatile("s_waitcnt vmcnt(6)" ::: "memory");
  __builtin_amdgcn_s_barrier();

  bf16x8 a[4][2], b0[2][2], b1[2][2];
  for (int it = 0; it < (NT >> 1); ++it) {
    const int e = 2 * it;
    const int ep = (e + 2 < NT) ? e + 2 : NT - 1;
    const int op = (e + 3 < NT) ? e + 3 : NT - 1;
    // ph1
    ldA(a, 0, 0); ldB(b0, 0, 0);
    __builtin_amdgcn_s_barrier();
    MMQ(0, 0, a, b0);
    __builtin_amdgcn_s_barrier();
    // ph2
    ldB(b1, 0, 1);
    __builtin_amdgcn_s_barrier();
    MMQ(0, 1, a, b1);
    __builtin_amdgcn_s_barrier();
    // ph3
    ldA(a, 0, 1); stage(1, 0, ep, 0);
    __builtin_amdgcn_s_barrier();
    MMQ(1, 1, a, b1);
    __builtin_amdgcn_s_barrier();
    // ph4
    stage(1, 1, ep, 0);
    asm volatile("s_waitcnt vmcnt(4)" ::: "memory");
    __builtin_amdgcn_s_barrier();
    MMQ(1, 0, a, b0);
    __builtin_amdgcn_s_barrier();
    // ph5
    ldA(a, 1, 0); ldB(b0, 1, 0); stage(0, 0, ep, 0);
    __builtin_amdgcn_s_barrier();
    MMQ(0, 0, a, b0);
    __builtin_amdgcn_s_barrier();
    // ph6
    ldB(b1, 1, 1); stage(0, 1, ep, 0);
    __builtin_amdgcn_s_barrier();
    MMQ(0, 1, a, b1);
    __builtin_amdgcn_s_barrier();
    // ph7
    ldA(a, 1, 1); stage(1, 0, op, 1);
    __builtin_amdgcn_s_barrier();
    MMQ(1, 1, a, b1);
    __builtin_amdgcn_s_barrier();
    // ph8
    stage(1, 1, op, 1); stage(0, 0, op, 1); stage(0, 1, op, 1);
    asm volatile("s_waitcnt vmcnt(6)" ::: "memory");
    __builtin_amdgcn_s_barrier();
    MMQ(1, 0, a, b0);
    __builtin_amdgcn_s_barrier();
  }
  asm volatile("s_waitcnt vmcnt(0)" ::: "memory");

#pragma unroll
  for (int i = 0; i < 8; i++)
#pragma unroll
    for (int j = 0; j < 4; j++)
#pragma unroll
      for (int r = 0; r < 4; r++) {
        int row = bm * 256 + wm * 128 + i * 16 + ((lane >> 4) << 2) + r;
        int col = bn * 256 + wn * 64 + j * 16 + (lane & 15);
        size_t idx = (size_t)row * N + col;
        float v = acc[i][j][r];
        if (EPI == 0) {
          ((__bf16*)Cout)[idx] = (__bf16)v;
        } else if (EPI == 1) {
          ((float*)Cout)[idx] = v + res[idx];
        } else {
          float u = 0.7978845608028654f * (v + 0.044715f * v * v * v);
          ((__bf16*)Cout)[idx] = (__bf16)(0.5f * v * (1.0f + tanhf(u)));
        }
      }
}

// ---------------------------------------------------------------------------
// RoPE tables, interleaved: tab[s*64+j] = {cos, sin}. 1 MB.
// ---------------------------------------------------------------------------
__global__ __launch_bounds__(256) void rope_tables(float2* __restrict__ tab) {
  const int idx = blockIdx.x * 256 + threadIdx.x;  // 131072
  const int s = idx >> 6, j = idx & 63;
  const float inv = powf(10000.0f, -(float)j / 64.0f);
  const float a = (float)s * inv;
  tab[idx] = make_float2(cosf(a), sinf(a));
}

// ---------------------------------------------------------------------------
// Flash attention v2 (causal). QBLK=128 (8 waves x 16 q-rows), KVBLK=64.
// (unchanged — verified)
// ---------------------------------------------------------------------------
__global__ __launch_bounds__(512) void flash_attn(
    const __bf16* __restrict__ qg, const __bf16* __restrict__ kg,
    const __bf16* __restrict__ vtg, __bf16* __restrict__ og) {
  __shared__ char lds[81920];
  const int tid = threadIdx.x, lane = tid & 63, w = tid >> 6;  // w 0..7
  const int h = blockIdx.y, b = blockIdx.z;
  const int bh = b * 16 + h;
  const __bf16* qb = qg + (size_t)bh * 2048 * 128;
  const char* kbb = (const char*)(kg + (size_t)bh * 2048 * 128);
  const char* vbb = (const char*)(vtg + (size_t)bh * 128 * 2048);
  char* Pw = lds + 65536 + w * 2048;

  const char* gK[2];
  const char* gV[2];
#pragma unroll
  for (int t = 0; t < 2; t++) {
    int gg = t * 512 + tid;           // 0..1023
    int rk = gg >> 4, sk = gg & 15;   // K row 0..63, slot 0..15
    gK[t] = kbb + rk * 256 + ((sk ^ (rk & 15)) << 4);
    int rv = gg >> 3, sv = gg & 7;    // V row 0..127, slot 0..7
    gV[t] = vbb + rv * 4096 + ((sv ^ (rv & 7)) << 4);
  }

  const float SL2E = 0.08838834764831845f * 1.4426950408889634f;  // scale*log2(e)

  auto stageKV = [&](int kt, int buf) {
#pragma unroll
    for (int t = 0; t < 2; t++) {
      int gg = t * 512 + tid;
      gload16(gK[t] + (size_t)kt * 16384, lds + buf * 16384 + gg * 16);
      gload16(gV[t] + (size_t)kt * 128, lds + 32768 + buf * 16384 + gg * 16);
    }
  };

  auto run_qtile = [&](int qt) {
    const int qrow0 = qt * 128 + w * 16;
    bf16x8 qf[4];
#pragma unroll
    for (int c = 0; c < 4; c++) {
      bf16x8 raw = *(const bf16x8*)(qb + (size_t)(qrow0 + (lane & 15)) * 128 +
                                    c * 32 + ((lane >> 4) << 3));
#pragma unroll
      for (int e = 0; e < 8; e++) qf[c][e] = (__bf16)((float)raw[e] * SL2E);
    }
    float m[4], lsp[4];
    f32x4 o[8];
#pragma unroll
    for (int r = 0; r < 4; r++) { m[r] = -__builtin_inff(); lsp[r] = 0.f; }
#pragma unroll
    for (int n = 0; n < 8; n++) o[n] = (f32x4){0.f, 0.f, 0.f, 0.f};

    const int NKT = 2 * qt + 2;
    stageKV(0, 0);

    for (int kt = 0; kt < NKT; kt++) {
      const int cur = kt & 1;
      const char* Ks = lds + cur * 16384;
      const char* Vs = lds + 32768 + cur * 16384;
      if (kt < NKT - 1) {
        stageKV(kt + 1, cur ^ 1);
        asm volatile("s_waitcnt vmcnt(4)" ::: "memory");  // current tile landed
      } else {
        asm volatile("s_waitcnt vmcnt(0)" ::: "memory");
      }
      __builtin_amdgcn_s_barrier();

      f32x4 s[4];
      __builtin_amdgcn_s_setprio(1);
#pragma unroll
      for (int n = 0; n < 4; n++) {
        s[n] = (f32x4){0.f, 0.f, 0.f, 0.f};
#pragma unroll
        for (int c = 0; c < 4; c++) {
          int krow = n * 16 + (lane & 15);
          int c16 = c * 4 + (lane >> 4);
          bf16x8 kf = *(const bf16x8*)(Ks + krow * 256 + ((c16 ^ (krow & 15)) << 4));
          s[n] = __builtin_amdgcn_mfma_f32_16x16x32_bf16(qf[c], kf, s[n], 0, 0, 0);
        }
      }
      __builtin_amdgcn_s_setprio(0);

      if (kt * 64 + 63 > qrow0) {
#pragma unroll
        for (int r = 0; r < 4; r++) {
          const int qrow = qrow0 + ((lane >> 4) << 2) + r;
#pragma unroll
          for (int n = 0; n < 4; n++) {
            int col = kt * 64 + n * 16 + (lane & 15);
            if (col > qrow) s[n][r] = -__builtin_inff();
          }
        }
      }

      float tmx[4];
#pragma unroll
      for (int r = 0; r < 4; r++)
        tmx[r] = fmaxf(fmaxf(s[0][r], s[1][r]), fmaxf(s[2][r], s[3][r]));
      bool hot = (tmx[0] > m[0] + 8.f) | (tmx[1] > m[1] + 8.f) |
                 (tmx[2] > m[2] + 8.f) | (tmx[3] > m[3] + 8.f);
      if (__any(hot)) {
        float fc[4];
#pragma unroll
        for (int r = 0; r < 4; r++) {
          float gmx = tmx[r];
#pragma unroll
          for (int mk = 1; mk < 16; mk <<= 1) gmx = fmaxf(gmx, __shfl_xor(gmx, mk));
          float nm = fmaxf(m[r], gmx);
          fc[r] = __builtin_amdgcn_exp2f(m[r] - nm);
          m[r] = nm;
          lsp[r] *= fc[r];
        }
#pragma unroll
        for (int n = 0; n < 8; n++) {
          o[n][0] *= fc[0]; o[n][1] *= fc[1]; o[n][2] *= fc[2]; o[n][3] *= fc[3];
        }
      }

      float p[4][4];
#pragma unroll
      for (int r = 0; r < 4; r++) {
        float sum = 0.f;
#pragma unroll
        for (int n = 0; n < 4; n++) {
          float pv = __builtin_amdgcn_exp2f(s[n][r] - m[r]);
          p[n][r] = pv;
          sum += pv;
        }
        lsp[r] += sum;
      }

#pragma unroll
      for (int n = 0; n < 4; n++)
#pragma unroll
        for (int r = 0; r < 4; r++) {
          int prow = ((lane >> 4) << 2) + r;
          int col = n * 16 + (lane & 15);
          int ch = col >> 3;
          *(__bf16*)(Pw + prow * 128 + ((ch ^ (prow & 7)) << 4) + ((col & 7) << 1)) =
              (__bf16)p[n][r];
        }

      __builtin_amdgcn_s_setprio(1);
#pragma unroll
      for (int kk = 0; kk < 2; kk++) {
        int prow = lane & 15;
        int pc = kk * 4 + (lane >> 4);
        bf16x8 pf = *(const bf16x8*)(Pw + prow * 128 + ((pc ^ (prow & 7)) << 4));
#pragma unroll
        for (int n = 0; n < 8; n++) {
          int vr = n * 16 + (lane & 15);
          bf16x8 vf = *(const bf16x8*)(Vs + vr * 128 + ((pc ^ (vr & 7)) << 4));
          o[n] = __builtin_amdgcn_mfma_f32_16x16x32_bf16(pf, vf, o[n], 0, 0, 0);
        }
      }
      __builtin_amdgcn_s_setprio(0);
      __builtin_amdgcn_s_barrier();
    }

    float inv[4];
#pragma unroll
    for (int r = 0; r < 4; r++) {
      float ls = lsp[r];
#pragma unroll
      for (int mk = 1; mk < 16; mk <<= 1) ls += __shfl_xor(ls, mk);
      inv[r] = 1.0f / ls;
    }
#pragma unroll
    for (int n = 0; n < 8; n++)
#pragma unroll
      for (int r = 0; r < 4; r++) {
        int qrow = qrow0 + ((lane >> 4) << 2) + r;
        og[(size_t)(b * 2048 + qrow) * 2048 + h * 128 + n * 16 + (lane & 15)] =
            (__bf16)(o[n][r] * inv[r]);
      }
  };

  run_qtile(15 - (int)blockIdx.x);
  run_qtile((int)blockIdx.x);
}

// ---------------------------------------------------------------------------
extern "C" void kernel_launch(void* const* d_in, const int* in_sizes, int n_in,
                              void* d_out, int out_size, void* d_ws, size_t ws_size,
                              hipStream_t stream) {
  const float* x = (const float*)d_in[0];
  const float* w_qkv = (const float*)d_in[1];
  const float* w_out = (const float*)d_in[2];
  const float* w_fc = (const float*)d_in[3];
  const float* w_proj = (const float*)d_in[4];
  const float* g_in = (const float*)d_in[5];
  const float* g_ff = (const float*)d_in[6];
  float* out = (float*)d_out;
  char* ws = (char*)d_ws;

  constexpr size_t O_WQKV = 0;           // bf16 [6144][2048]
  constexpr size_t O_WOUT = 25165824;    // bf16 [2048][2048]
  constexpr size_t O_WFC = 33554432;     // bf16 [4096][2048]
  constexpr size_t O_WPROJ = 50331648;   // bf16 [2048][4096]
  constexpr size_t O_H = 67108864;       // bf16 [4096][2048]
  constexpr size_t O_QKV = 83886080;     // bf16 fcact [4096][4096]
  constexpr size_t O_Q = 134217728;      // bf16 [2][16][2048][128]
  constexpr size_t O_K = 150994944;
  constexpr size_t O_VT = 167772160;     // bf16 [2][16][128][2048]
  constexpr size_t O_TAB = 184549376;    // float2 cos/sin [2048][64] (1 MB)
  constexpr size_t O_ATTN = 185597952;   // bf16 [4096][2048]
  constexpr size_t O_X1 = 202375168;     // f32 [4096][2048]

  __bf16* wqkvT = (__bf16*)(ws + O_WQKV);
  __bf16* woutT = (__bf16*)(ws + O_WOUT);
  __bf16* wfcT = (__bf16*)(ws + O_WFC);
  __bf16* wprojT = (__bf16*)(ws + O_WPROJ);
  __bf16* h = (__bf16*)(ws + O_H);
  __bf16* fcact = (__bf16*)(ws + O_QKV);
  __bf16* qr = (__bf16*)(ws + O_Q);
  __bf16* kr = (__bf16*)(ws + O_K);
  __bf16* vt = (__bf16*)(ws + O_VT);
  float2* tab = (float2*)(ws + O_TAB);
  __bf16* attn = (__bf16*)(ws + O_ATTN);
  float* x1 = (float*)(ws + O_X1);

  // weight convert+transpose (64x64 tiles)
  transpose_cvt<<<dim3(96, 32), 256, 0, stream>>>(w_qkv, wqkvT, 2048, 6144);
  transpose_cvt<<<dim3(32, 32), 256, 0, stream>>>(w_out, woutT, 2048, 2048);
  transpose_cvt<<<dim3(64, 32), 256, 0, stream>>>(w_fc, wfcT, 2048, 4096);
  transpose_cvt<<<dim3(32, 64), 256, 0, stream>>>(w_proj, wprojT, 4096, 2048);

  // rope tables (needed by gemm_qkv epilogue)
  rope_tables<<<512, 256, 0, stream>>>(tab);
  // h = rmsnorm(x, g_in)
  rmsnorm_kernel<<<4096, 256, 0, stream>>>(x, g_in, h);
  // q,k (roped) + v^T directly from the qkv GEMM epilogue
  gemm_qkv<<<dim3(48, 32), 256, 0, stream>>>(h, wqkvT, tab, qr, kr, vt, 2048);
  // attention (QBLK=128, balanced pairs)
  flash_attn<<<dim3(8, 16, 2), 512, 0, stream>>>(qr, kr, vt, attn);
  // x1 = x + attn @ w_out
  gemm_bt<1><<<dim3(16, 32), 256, 0, stream>>>(attn, woutT, (void*)x1, x, 4096, 2048, 2048);
  // h2 = rmsnorm(x1, g_ff)
  rmsnorm_kernel<<<4096, 256, 0, stream>>>(x1, g_ff, h);
  // fcact = gelu(h2 @ w_fc)  (256^2 8-phase, grid 16x16 = exactly 1 round)
  gemm256<2><<<dim3(16, 16), 512, 0, stream>>>(h, wfcT, (void*)fcact, nullptr, 4096, 4096, 2048);
  // out = x1 + fcact @ w_proj
  gemm_bt<1><<<dim3(16, 32), 256, 0, stream>>>(fcact, wprojT, (void*)out, x1, 4096, 2048, 4096);
}